// Round 9
// baseline (627.064 us; speedup 1.0000x reference)
//
#include <hip/hip_runtime.h>
#include <hip/hip_bf16.h>
#include <math.h>

#define NNODES 30000
#define NEDGES 480000
#define RROWS  8192
#define NCOLS  128
#define NIN    128
#define EIN    64
#define NHID   256
#define EHID   128
#define NOUTD  256
#define EOUTD  64
#define NCLS   10
#define NB_PFX 118   // ceil(30000/256)

typedef __attribute__((ext_vector_type(8))) unsigned short ushort8;
typedef __attribute__((ext_vector_type(8))) short bhalf8;
typedef __attribute__((ext_vector_type(4))) float floatx4;

__device__ __forceinline__ float lrelu(float v){ return v > 0.f ? v : 0.01f * v; }
__device__ __forceinline__ float4 ld4(const float* p){ return *(const float4*)p; }
__device__ __forceinline__ float4 ntld4(const float* p){
    floatx4 v = __builtin_nontemporal_load((const floatx4*)p);
    return make_float4(v.x, v.y, v.z, v.w);
}
__device__ __forceinline__ void ntst4(float* p, float4 v){
    floatx4 n = {v.x, v.y, v.z, v.w};
    __builtin_nontemporal_store(n, (floatx4*)p);
}
__device__ __forceinline__ void ntst8u(unsigned short* p, ushort8 v){
    __builtin_nontemporal_store(v, (ushort8*)p);
}
__device__ __forceinline__ unsigned short f2b(float f){
    unsigned int u = __builtin_bit_cast(unsigned int, f);
    u += 0x7fffu + ((u >> 16) & 1u);
    return (unsigned short)(u >> 16);
}
__device__ __forceinline__ float b2f(unsigned short b){
    unsigned int u = ((unsigned int)b) << 16;
    return __builtin_bit_cast(float, u);
}

// ---------------- fused prep ----------------
#define PREP_CVT_N   1875
#define PREP_W1T_B   (PREP_CVT_N)
#define PREP_W1B_B   (PREP_W1T_B + 64)
#define PREP_W2T_B   (PREP_W1B_B + 32)
#define PREP_W2B_B   (PREP_W2T_B + 64)
#define PREP_W1N_B   (PREP_W2B_B + 32)
#define PREP_W2N_B   (PREP_W1N_B + 256)
#define PREP_HIST_B  (PREP_W2N_B + 320)
#define PREP_DET_B   (PREP_HIST_B + 1875)
#define PREP_TOTAL   (PREP_DET_B + 1)

__device__ __forceinline__ void wT_region(const float* __restrict__ W, unsigned short* __restrict__ Wt,
                                          int KOFF, int KSUB, int N, int idx){
    if (idx >= N * KSUB) return;
    int n = idx / KSUB, k = idx % KSUB;
    Wt[idx] = f2b(W[(size_t)(KOFF + k) * N + n]);
}

__global__ __launch_bounds__(256) void k_prep(
    const float* __restrict__ x, unsigned short* __restrict__ xb,
    const float* __restrict__ W1e, unsigned short* __restrict__ W1tT, unsigned short* __restrict__ W1bT,
    const float* __restrict__ W2e, unsigned short* __restrict__ W2tT, unsigned short* __restrict__ W2bT,
    const float* __restrict__ W1n, unsigned short* __restrict__ W1nTb,
    const float* __restrict__ W2n, unsigned short* __restrict__ W2nTb,
    const int* __restrict__ dst, int* __restrict__ cnt_i,
    const unsigned int* __restrict__ mask, int* __restrict__ mode)
{
    const int bid = blockIdx.x, t = threadIdx.x;
    if (bid < PREP_CVT_N){
        int i = bid * 256 + t;
        float4 a = ntld4(x + (size_t)i * 8), b = ntld4(x + (size_t)i * 8 + 4);
        ushort8 o = {f2b(a.x), f2b(a.y), f2b(a.z), f2b(a.w), f2b(b.x), f2b(b.y), f2b(b.z), f2b(b.w)};
        *(ushort8*)(xb + (size_t)i * 8) = o;
    } else if (bid < PREP_W1B_B){
        wT_region(W1e, W1tT, 0, 128, 128, (bid - PREP_W1T_B) * 256 + t);
    } else if (bid < PREP_W2T_B){
        wT_region(W1e, W1bT, 128, 64, 128, (bid - PREP_W1B_B) * 256 + t);
    } else if (bid < PREP_W2B_B){
        wT_region(W2e, W2tT, 0, 256, 64, (bid - PREP_W2T_B) * 256 + t);
    } else if (bid < PREP_W1N_B){
        wT_region(W2e, W2bT, 256, 128, 64, (bid - PREP_W2B_B) * 256 + t);
    } else if (bid < PREP_W2N_B){
        wT_region(W1n, W1nTb, 0, 256, 256, (bid - PREP_W1N_B) * 256 + t);
    } else if (bid < PREP_HIST_B){
        wT_region(W2n, W2nTb, 0, 320, 256, (bid - PREP_W2N_B) * 256 + t);
    } else if (bid < PREP_DET_B){
        int i = (bid - PREP_HIST_B) * 256 + t;
        if (i < NEDGES) atomicAdd(&cnt_i[dst[i]], 1);
    } else if (t == 0){
        bool allI32 = true, allF32 = true;
        for (int i = 0; i < 64; i++){
            unsigned int v = mask[i];
            if (!(v == 0u || v == 1u)) allI32 = false;
            if (!(v == 0u || v == 0x3F800000u)) allF32 = false;
        }
        *mode = allI32 ? 0 : (allF32 ? 1 : 2);
    }
}

// ---------------- 3-stage exclusive prefix ----------------
__global__ __launch_bounds__(256) void k_pfx1(const int* __restrict__ cnt_i, int* __restrict__ blocksum){
    __shared__ int red[256];
    const int t = threadIdx.x;
    const int i = blockIdx.x * 256 + t;
    red[t] = (i < NNODES) ? cnt_i[i] : 0;
    __syncthreads();
    for (int o = 128; o; o >>= 1){ if (t < o) red[t] += red[t + o]; __syncthreads(); }
    if (t == 0) blocksum[blockIdx.x] = red[0];
}
__global__ __launch_bounds__(128) void k_pfx2(const int* __restrict__ blocksum, int* __restrict__ blockoff){
    __shared__ int s[128];
    const int t = threadIdx.x;
    int v = (t < NB_PFX) ? blocksum[t] : 0;
    s[t] = v;
    __syncthreads();
    for (int o = 1; o < 128; o <<= 1){
        int add = (t >= o) ? s[t - o] : 0;
        __syncthreads();
        s[t] += add;
        __syncthreads();
    }
    if (t < NB_PFX) blockoff[t] = s[t] - v;
}
__global__ __launch_bounds__(256) void k_pfx3(const int* __restrict__ cnt_i, const int* __restrict__ blockoff,
                                              int* __restrict__ cursor, float* __restrict__ cntf){
    __shared__ int s[256];
    const int t = threadIdx.x;
    const int i = blockIdx.x * 256 + t;
    int v = (i < NNODES) ? cnt_i[i] : 0;
    s[t] = v;
    __syncthreads();
    for (int o = 1; o < 256; o <<= 1){
        int add = (t >= o) ? s[t - o] : 0;
        __syncthreads();
        s[t] += add;
        __syncthreads();
    }
    if (i < NNODES){
        cursor[i] = s[t] - v + blockoff[blockIdx.x];
        cntf[i] = (float)v;
    }
}

__global__ void k_scatter(const int* __restrict__ dst, int* __restrict__ cursor, int* __restrict__ eidx){
    int i = blockIdx.x * 256 + threadIdx.x;
    if (i >= NEDGES) return;
    int pos = atomicAdd(&cursor[dst[i]], 1);
    eidx[pos] = i;
}
__global__ void k_sgather(const int* __restrict__ src, const int* __restrict__ dst,
                          const int* __restrict__ eidx,
                          int* __restrict__ srcs, int* __restrict__ dsts){
    int p = blockIdx.x * 256 + threadIdx.x;
    if (p >= NEDGES) return;
    int i = eidx[p];
    srcs[p] = src[i];
    dsts[p] = dst[i];
}

// ---------------- small GEMM: out_bf16[M,N] = Ab[M,K] @ Wt[N,K] ----------------
template<int K, int N>
__global__ __launch_bounds__(256) void k_gemm_b16(
    const unsigned short* __restrict__ Ab, const unsigned short* __restrict__ Wt,
    unsigned short* __restrict__ outb, int M)
{
    __shared__ unsigned short At[64][K + 8];
    const int t = threadIdx.x;
    const int r0 = blockIdx.x * 64;
    {
        const int r = t >> 2, q = t & 3;
        const int row = r0 + r;
        const bool valid = row < M;
        const unsigned short* a = Ab + (size_t)(valid ? row : 0) * K;
        for (int kk = q * (K / 4); kk < (q + 1) * (K / 4); kk += 8){
            ushort8 u;
            if (valid) u = *(const ushort8*)(a + kk);
            else       u = (ushort8){0,0,0,0,0,0,0,0};
            *(ushort8*)&At[r][kk] = u;
        }
    }
    __syncthreads();
    const int lane = t & 63, w = t >> 6;
    const int fr = lane & 15, fq = lane >> 4;
    constexpr int NF = N / 16;
    floatx4 acc[NF] = {};
    #pragma unroll
    for (int ks = 0; ks < K / 32; ks++){
        const int k = ks * 32 + fq * 8;
        bhalf8 a = *(bhalf8*)&At[w * 16 + fr][k];
        #pragma unroll
        for (int n = 0; n < NF; n++){
            bhalf8 b = *(const bhalf8*)(Wt + (size_t)(n * 16 + fr) * K + k);
            acc[n] = __builtin_amdgcn_mfma_f32_16x16x32_bf16(a, b, acc[n], 0, 0, 0);
        }
    }
    #pragma unroll
    for (int n = 0; n < NF; n++){
        const int col = n * 16 + fr;
        #pragma unroll
        for (int rr = 0; rr < 4; rr++){
            const int row = r0 + w * 16 + fq * 4 + rr;
            if (row < M) outb[(size_t)row * N + col] = f2b(acc[n][rr]);
        }
    }
}

// ---------------- fused edge layer 1 — 2-tile software pipeline ----------------
__global__ __launch_bounds__(256) void k_edge1_fused(
    const float* __restrict__ e,
    const int* __restrict__ srcs, const int* __restrict__ dsts, const int* __restrict__ eidx,
    const unsigned short* __restrict__ W1bT, const float* __restrict__ b1e,
    const unsigned short* __restrict__ P1b, const unsigned short* __restrict__ W2bT,
    unsigned short* __restrict__ Qb, float* __restrict__ hsum)
{
    __shared__ unsigned short Cb[64][136];
    __shared__ unsigned short P1s[64][136];
    __shared__ int dstS[64];
    const int t = threadIdx.x;
    const int r = t >> 2, q = t & 3;
    const int lane = t & 63, w = t >> 6;
    const int wm = w >> 1, wn = w & 1;
    const int fr = lane & 15, fq = lane >> 4;
    const int base = blockIdx.x * 128;

    float4 f0, f1, f2, f3;
    ushort8 u0, u1, u2, u3;
    int dcur;

    // load tile regs (e rows nt; P1 rows via L2)
    {
        const int p = base + r;
        dcur = dsts[p];
        const int srow = srcs[p];
        const int ei = eidx[p];
        const float* ep = e + (size_t)ei * 64 + q * 16;
        f0 = ntld4(ep); f1 = ntld4(ep + 4); f2 = ntld4(ep + 8); f3 = ntld4(ep + 12);
        const unsigned short* pp = P1b + (size_t)srow * 128 + q * 32;
        u0 = *(const ushort8*)pp;       u1 = *(const ushort8*)(pp + 8);
        u2 = *(const ushort8*)(pp + 16); u3 = *(const ushort8*)(pp + 24);
    }

    #pragma unroll
    for (int tile = 0; tile < 2; tile++){
        const int p0 = base + tile * 64;
        if (tile) __syncthreads();     // previous tile's LDS reads complete
        // write LDS from regs
        if (q == 0) dstS[r] = dcur;
        {
            ushort8 e0 = {f2b(f0.x), f2b(f0.y), f2b(f0.z), f2b(f0.w), f2b(f1.x), f2b(f1.y), f2b(f1.z), f2b(f1.w)};
            ushort8 e1v = {f2b(f2.x), f2b(f2.y), f2b(f2.z), f2b(f2.w), f2b(f3.x), f2b(f3.y), f2b(f3.z), f2b(f3.w)};
            *(ushort8*)&Cb[r][q * 16]     = e0;
            *(ushort8*)&Cb[r][q * 16 + 8] = e1v;
            *(ushort8*)&P1s[r][q * 32]      = u0;
            *(ushort8*)&P1s[r][q * 32 + 8]  = u1;
            *(ushort8*)&P1s[r][q * 32 + 16] = u2;
            *(ushort8*)&P1s[r][q * 32 + 24] = u3;
        }
        __syncthreads();
        // prefetch next tile into regs (overlaps with compute below)
        if (tile == 0){
            const int p = base + 64 + r;
            dcur = dsts[p];
            const int srow = srcs[p];
            const int ei = eidx[p];
            const float* ep = e + (size_t)ei * 64 + q * 16;
            f0 = ntld4(ep); f1 = ntld4(ep + 4); f2 = ntld4(ep + 8); f3 = ntld4(ep + 12);
            const unsigned short* pp = P1b + (size_t)srow * 128 + q * 32;
            u0 = *(const ushort8*)pp;       u1 = *(const ushort8*)(pp + 8);
            u2 = *(const ushort8*)(pp + 16); u3 = *(const ushort8*)(pp + 24);
        }
        // phase B: acc1 = e_tile @ W1bT
        floatx4 acc1[2][4] = {};
        #pragma unroll
        for (int ks = 0; ks < 2; ks++){
            const int k = ks * 32 + fq * 8;
            bhalf8 a0 = *(bhalf8*)&Cb[wm * 32 + fr][k];
            bhalf8 a1 = *(bhalf8*)&Cb[wm * 32 + 16 + fr][k];
            #pragma unroll
            for (int n = 0; n < 4; n++){
                const int col = wn * 64 + n * 16 + fr;
                bhalf8 b = *(const bhalf8*)(W1bT + (size_t)col * 64 + k);
                acc1[0][n] = __builtin_amdgcn_mfma_f32_16x16x32_bf16(a0, b, acc1[0][n], 0, 0, 0);
                acc1[1][n] = __builtin_amdgcn_mfma_f32_16x16x32_bf16(a1, b, acc1[1][n], 0, 0, 0);
            }
        }
        __syncthreads();
        // phase C: e1 = leaky(acc1 + P1s + b1e) -> Cb
        #pragma unroll
        for (int m = 0; m < 2; m++){
            #pragma unroll
            for (int n = 0; n < 4; n++){
                const int col = wn * 64 + n * 16 + fr;
                const float bv = b1e[col];
                #pragma unroll
                for (int rr = 0; rr < 4; rr++){
                    const int row = wm * 32 + m * 16 + fq * 4 + rr;
                    const float pv = b2f(P1s[row][col]);
                    Cb[row][col] = f2b(lrelu(acc1[m][n][rr] + pv + bv));
                }
            }
        }
        __syncthreads();
        // phase D: Q = e1 @ W2bT -> stage into P1s
        {
            floatx4 acc2[4] = {};
            #pragma unroll
            for (int ks = 0; ks < 4; ks++){
                const int k = ks * 32 + fq * 8;
                bhalf8 a = *(bhalf8*)&Cb[w * 16 + fr][k];
                #pragma unroll
                for (int n = 0; n < 4; n++){
                    bhalf8 b = *(const bhalf8*)(W2bT + (size_t)(n * 16 + fr) * 128 + k);
                    acc2[n] = __builtin_amdgcn_mfma_f32_16x16x32_bf16(a, b, acc2[n], 0, 0, 0);
                }
            }
            #pragma unroll
            for (int n = 0; n < 4; n++){
                const int col = n * 16 + fr;
                #pragma unroll
                for (int rr = 0; rr < 4; rr++){
                    const int row = w * 16 + fq * 4 + rr;
                    P1s[row][col] = f2b(acc2[n][rr]);
                }
            }
        }
        __syncthreads();
        // coalesced Q store
        {
            unsigned short* op = Qb + (size_t)(p0 + r) * 64 + q * 16;
            ntst8u(op,     *(ushort8*)&P1s[r][q * 16]);
            ntst8u(op + 8, *(ushort8*)&P1s[r][q * 16 + 8]);
        }
        // phase E: run-reduced scatter-add of e1 to h1sum
        {
            const int col = t & 127, half = t >> 7;
            const int rbase = half * 32;
            float s = 0.f;
            int prev = dstS[rbase];
            #pragma unroll 4
            for (int rr = 0; rr < 32; rr++){
                const int rw2 = rbase + rr;
                const int d = dstS[rw2];
                if (d != prev){
                    atomicAdd(&hsum[(size_t)prev * EHID + col], s);
                    s = 0.f; prev = d;
                }
                s += b2f(Cb[rw2][col]);
            }
            atomicAdd(&hsum[(size_t)prev * EHID + col], s);
        }
    }
}

// ---------------- edge layer 2 (lite) ----------------
__global__ __launch_bounds__(256) void k_edge2_lite(
    const unsigned short* __restrict__ P2b, const unsigned short* __restrict__ Qb,
    const int* __restrict__ srcs, const int* __restrict__ dsts,
    const float* __restrict__ b2e, float* __restrict__ hsum)
{
    const int t = threadIdx.x;
    const int lane = t & 63, w = t >> 6;
    const int p0 = blockIdx.x * 256 + w * 64;
    const float bias = b2e[lane];
    float s = 0.f;
    int prev = dsts[p0];
    #pragma unroll 4
    for (int i = 0; i < 64; i++){
        const int p = p0 + i;
        const int d = dsts[p];
        if (d != prev){
            atomicAdd(&hsum[(size_t)prev * EOUTD + lane], s);
            s = 0.f; prev = d;
        }
        const float q  = b2f(__builtin_nontemporal_load(&Qb[(size_t)p * 64 + lane]));
        const float pv = b2f(P2b[(size_t)srcs[p] * 64 + lane]);
        s += lrelu(pv + q + bias);
    }
    atomicAdd(&hsum[(size_t)prev * EOUTD + lane], s);
}

// ---------------- node1 + fused P2: x1b = leaky([xb, h1/cnt]@W1n+b); P2 = x1b @ W2tT ----------------
__global__ __launch_bounds__(256) void k_node1_p2(
    const unsigned short* __restrict__ A1b, const float* __restrict__ hsum,
    const float* __restrict__ cntf,
    const unsigned short* __restrict__ Wt, const float* __restrict__ bias,
    const unsigned short* __restrict__ W2tT,
    unsigned short* __restrict__ x1b, unsigned short* __restrict__ P2b, int M)
{
    constexpr int K = 256;
    __shared__ unsigned short At[32][K + 8];
    const int t = threadIdx.x;
    const int r0 = blockIdx.x * 32;
    {
        const int r = t >> 3, q = t & 7;
        const int row = r0 + r;
        const bool valid = row < M;
        float rinv = 0.f;
        const unsigned short* a1 = A1b;
        const float* a2 = hsum;
        if (valid){
            rinv = 1.f / fmaxf(cntf[row], 1.f);
            a1 = A1b  + (size_t)row * NIN;
            a2 = hsum + (size_t)row * EHID;
        }
        for (int kk = q * 32; kk < q * 32 + 32; kk += 8){
            ushort8 u;
            if (!valid){
                u = (ushort8){0,0,0,0,0,0,0,0};
            } else if (kk < NIN){
                u = *(const ushort8*)(a1 + kk);
            } else {
                float4 g0 = ld4(a2 + (kk - NIN)), g1 = ld4(a2 + (kk - NIN) + 4);
                u = (ushort8){f2b(g0.x*rinv), f2b(g0.y*rinv), f2b(g0.z*rinv), f2b(g0.w*rinv),
                              f2b(g1.x*rinv), f2b(g1.y*rinv), f2b(g1.z*rinv), f2b(g1.w*rinv)};
            }
            *(ushort8*)&At[r][kk] = u;
        }
    }
    __syncthreads();
    const int lane = t & 63, w = t >> 6;
    const int wm = w >> 1, wn = w & 1;
    const int fr = lane & 15, fq = lane >> 4;
    floatx4 acc[8] = {};
    #pragma unroll
    for (int ks = 0; ks < 8; ks++){
        const int k = ks * 32 + fq * 8;
        bhalf8 a = *(bhalf8*)&At[wm * 16 + fr][k];
        #pragma unroll
        for (int n = 0; n < 8; n++){
            const int col = wn * 128 + n * 16 + fr;
            bhalf8 b = *(const bhalf8*)(Wt + (size_t)col * K + k);
            acc[n] = __builtin_amdgcn_mfma_f32_16x16x32_bf16(a, b, acc[n], 0, 0, 0);
        }
    }
    __syncthreads();   // done reading At as input; reuse for x1 tile
    #pragma unroll
    for (int n = 0; n < 8; n++){
        const int col = wn * 128 + n * 16 + fr;
        const float bv = bias[col];
        #pragma unroll
        for (int rr = 0; rr < 4; rr++){
            const int row = r0 + wm * 16 + fq * 4 + rr;
            unsigned short ob = f2b(lrelu(acc[n][rr] + bv));
            At[wm * 16 + fq * 4 + rr][col] = ob;
            if (row < M) x1b[(size_t)row * 256 + col] = ob;
        }
    }
    __syncthreads();
    // P2 = x1 tile @ W2tT  (32x64, K=256)
    {
        floatx4 acc2[2] = {};
        #pragma unroll
        for (int ks = 0; ks < 8; ks++){
            const int k = ks * 32 + fq * 8;
            bhalf8 a = *(bhalf8*)&At[wm * 16 + fr][k];
            #pragma unroll
            for (int n = 0; n < 2; n++){
                const int col = wn * 32 + n * 16 + fr;
                bhalf8 b = *(const bhalf8*)(W2tT + (size_t)col * 256 + k);
                acc2[n] = __builtin_amdgcn_mfma_f32_16x16x32_bf16(a, b, acc2[n], 0, 0, 0);
            }
        }
        #pragma unroll
        for (int n = 0; n < 2; n++){
            const int col = wn * 32 + n * 16 + fr;
            #pragma unroll
            for (int rr = 0; rr < 4; rr++){
                const int row = r0 + wm * 16 + fq * 4 + rr;
                if (row < M) P2b[(size_t)row * 64 + col] = f2b(acc2[n][rr]);
            }
        }
    }
}

// ---------------- node2 (bf16-out only) ----------------
__global__ __launch_bounds__(256) void k_node2(
    const unsigned short* __restrict__ A1b, const float* __restrict__ hsum,
    const float* __restrict__ cntf,
    const unsigned short* __restrict__ Wt, const float* __restrict__ bias,
    unsigned short* __restrict__ outb, int M)
{
    constexpr int K = 320;
    __shared__ unsigned short At[32][K + 8];
    const int t = threadIdx.x;
    const int r0 = blockIdx.x * 32;
    {
        const int r = t >> 3, q = t & 7;
        const int row = r0 + r;
        const bool valid = row < M;
        float rinv = 0.f;
        const unsigned short* a1 = A1b;
        const float* a2 = hsum;
        if (valid){
            rinv = 1.f / fmaxf(cntf[row], 1.f);
            a1 = A1b  + (size_t)row * NHID;
            a2 = hsum + (size_t)row * EOUTD;
        }
        for (int kk = q * 40; kk < q * 40 + 40; kk += 8){
            ushort8 u;
            if (!valid){
                u = (ushort8){0,0,0,0,0,0,0,0};
            } else if (kk < NHID){
                u = *(const ushort8*)(a1 + kk);
            } else {
                float4 g0 = ld4(a2 + (kk - NHID)), g1 = ld4(a2 + (kk - NHID) + 4);
                u = (ushort8){f2b(g0.x*rinv), f2b(g0.y*rinv), f2b(g0.z*rinv), f2b(g0.w*rinv),
                              f2b(g1.x*rinv), f2b(g1.y*rinv), f2b(g1.z*rinv), f2b(g1.w*rinv)};
            }
            *(ushort8*)&At[r][kk] = u;
        }
    }
    __syncthreads();
    const int lane = t & 63, w = t >> 6;
    const int wm = w >> 1, wn = w & 1;
    const int fr = lane & 15, fq = lane >> 4;
    floatx4 acc[8] = {};
    #pragma unroll
    for (int ks = 0; ks < 10; ks++){
        const int k = ks * 32 + fq * 8;
        bhalf8 a = *(bhalf8*)&At[wm * 16 + fr][k];
        #pragma unroll
        for (int n = 0; n < 8; n++){
            const int col = wn * 128 + n * 16 + fr;
            bhalf8 b = *(const bhalf8*)(Wt + (size_t)col * K + k);
            acc[n] = __builtin_amdgcn_mfma_f32_16x16x32_bf16(a, b, acc[n], 0, 0, 0);
        }
    }
    #pragma unroll
    for (int n = 0; n < 8; n++){
        const int col = wn * 128 + n * 16 + fr;
        const float bv = bias[col];
        #pragma unroll
        for (int rr = 0; rr < 4; rr++){
            const int row = r0 + wm * 16 + fq * 4 + rr;
            if (row < M) outb[(size_t)row * 256 + col] = f2b(lrelu(acc[n][rr] + bv));
        }
    }
}

// ---------------- attention: q,k,v (x1 bf16) ----------------
__global__ __launch_bounds__(256) void k_attn_qkv(
    const unsigned short* __restrict__ x1b, const int* __restrict__ col_idx,
    const float* __restrict__ pe,
    const float* __restrict__ Wq, const float* __restrict__ Wk, const float* __restrict__ Wv,
    float* __restrict__ qo, float* __restrict__ ko, float* __restrict__ vo)
{
    __shared__ float c[256];
    const int i = blockIdx.x, t = threadIdx.x;
    const int col = col_idx[i];
    c[t] = b2f(x1b[(size_t)col * 256 + t]) + pe[i * 256 + t];
    __syncthreads();
    float aq = 0.f, ak = 0.f, av = 0.f;
    #pragma unroll 4
    for (int kk = 0; kk < 256; kk++){
        float cv = c[kk];
        aq += cv * Wq[kk * 256 + t];
        ak += cv * Wk[kk * 256 + t];
        av += cv * Wv[kk * 256 + t];
    }
    qo[i * 256 + t] = aq; ko[i * 256 + t] = ak; vo[i * 256 + t] = av;
}

// ---------------- attention: dist ----------------
__global__ __launch_bounds__(128) void k_attn_dist(
    const float* __restrict__ q, const float* __restrict__ k, float* __restrict__ dist)
{
    __shared__ float qr[256];
    __shared__ float red[128];
    const int i = blockIdx.x, t = threadIdx.x;
    qr[t] = q[i * 256 + t]; qr[t + 128] = q[i * 256 + t + 128];
    __syncthreads();
    float s = 0.f;
    #pragma unroll 4
    for (int kk = 0; kk < 256; kk++) s += qr[kk] * k[t * 256 + kk];
    s *= 0.0625f;
    red[t] = s; __syncthreads();
    for (int off = 64; off; off >>= 1){ if (t < off) red[t] = fmaxf(red[t], red[t + off]); __syncthreads(); }
    float m = red[0]; __syncthreads();
    float ex = expf(s - m);
    red[t] = ex; __syncthreads();
    for (int off = 64; off; off >>= 1){ if (t < off) red[t] += red[t + off]; __syncthreads(); }
    dist[i * 128 + t] = ex / red[0];
}

// ---------------- attention tail ----------------
__global__ __launch_bounds__(256) void k_attn_out(
    const float* __restrict__ dist, const float* __restrict__ v,
    const float* __restrict__ Wref, const float* __restrict__ bref,
    const float* __restrict__ Wc, const float* __restrict__ bep,
    float* __restrict__ colWc)
{
    __shared__ float dr[128];
    __shared__ float c2[256];
    __shared__ float nc[256];
    const int i = blockIdx.x, t = threadIdx.x;
    if (t < 128) dr[t] = dist[i * 128 + t];
    __syncthreads();
    float s = 0.f;
    #pragma unroll 4
    for (int j = 0; j < 128; j++) s += dr[j] * v[j * 256 + t];
    c2[t] = 2.f * s;
    __syncthreads();
    float a = 0.f;
    #pragma unroll 4
    for (int kk = 0; kk < 256; kk++) a += c2[kk] * Wref[kk * 256 + t];
    a += bref[t];
    nc[t] = 1.f / (1.f + expf(-a));
    __syncthreads();
    if (t < 64){
        float o = 0.f;
        #pragma unroll 4
        for (int kk = 0; kk < 256; kk++) o += nc[kk] * Wc[kk * 64 + t];
        colWc[i * 64 + t] = o + bep[t];
    }
}

// ---------------- rowWr = x2b[row_idx] @ Wr ----------------
__global__ __launch_bounds__(256) void k_rowwr(
    const unsigned short* __restrict__ x2b, const int* __restrict__ row_idx,
    const float* __restrict__ Wr, float* __restrict__ rw)
{
    __shared__ unsigned short A[16][264];
    const int t = threadIdx.x;
    const int r0 = blockIdx.x * 16;
    const int rl = t >> 4, cg = t & 15;
    const int ridx = row_idx[r0 + rl];
    const unsigned short* ar = x2b + (size_t)ridx * 256;
    for (int i = cg; i < 32; i += 16) *(ushort8*)&A[rl][i * 8] = *(const ushort8*)(ar + i * 8);
    __syncthreads();
    float acc[4] = {0.f, 0.f, 0.f, 0.f};
    #pragma unroll 4
    for (int kk = 0; kk < 256; kk++){
        float4 w = ld4(Wr + (size_t)kk * 64 + cg * 4);
        float a = b2f(A[rl][kk]);
        acc[0] += a * w.x; acc[1] += a * w.y; acc[2] += a * w.z; acc[3] += a * w.w;
    }
    *(float4*)(rw + (size_t)(r0 + rl) * 64 + cg * 4) = make_float4(acc[0], acc[1], acc[2], acc[3]);
}

// ---------------- fused: pred -> d_out (nt), imputation, classifier, log_softmax ----------------
__global__ __launch_bounds__(256) void k_pred8(
    const float* __restrict__ rowWr, const float* __restrict__ colWc,
    const void* __restrict__ maskp, const int* __restrict__ modep,
    const float* __restrict__ real, const float* __restrict__ Wcls, const float* __restrict__ bcls,
    float* __restrict__ out)
{
    __shared__ float colWc_s[8192];
    __shared__ float rowWr_s[8 * 64];
    __shared__ unsigned char mask_s[8 * 128];
    __shared__ float part[4][80];
    __shared__ float logits_s[80];
    const int t  = threadIdx.x;
    const int r0 = blockIdx.x * 8;
    const int mode = *modep;
    for (int idx = t; idx < 2048; idx += 256)
        *(float4*)&colWc_s[idx * 4] = ld4(colWc + idx * 4);
    for (int idx = t; idx < 128; idx += 256)
        *(float4*)&rowWr_s[idx * 4] = ld4(rowWr + (size_t)r0 * 64 + idx * 4);
    for (int idx = t; idx < 1024; idx += 256){
        const int g = idx >> 7, c = idx & 127;
        const int gi = (r0 + g) * 128 + c;
        bool m;
        if (mode == 2)      m = ((const unsigned char*)maskp)[gi] != 0;
        else if (mode == 0) m = ((const int*)maskp)[gi] != 0;
        else                m = ((const float*)maskp)[gi] != 0.f;
        mask_s[idx] = m ? 1 : 0;
    }
    __syncthreads();

    float acc[8][10];
    #pragma unroll
    for (int g = 0; g < 8; g++)
        #pragma unroll
        for (int c = 0; c < 10; c++) acc[g][c] = 0.f;
    float* pred = out + RROWS * NCLS;

    #pragma unroll 1
    for (int i = 0; i < 8; i++){
        const int e4   = i * 256 + t;
        const int base = e4 * 4;
        const int c = base >> 6;
        const int j = base & 63;
        float4 cw = ld4(&colWc_s[c * 64 + j]);
        float w40[40];
        #pragma unroll
        for (int u = 0; u < 10; u++){
            float4 wv = ld4(Wcls + (size_t)base * 10 + u * 4);
            w40[u*4+0] = wv.x; w40[u*4+1] = wv.y; w40[u*4+2] = wv.z; w40[u*4+3] = wv.w;
        }
        #pragma unroll
        for (int g = 0; g < 8; g++){
            const int rr = r0 + g;
            float4 rwv = ld4(&rowWr_s[g * 64 + j]);
            float4 p;
            p.x = lrelu(rwv.x + cw.x); p.y = lrelu(rwv.y + cw.y);
            p.z = lrelu(rwv.z + cw.z); p.w = lrelu(rwv.w + cw.w);
            ntst4(pred + (size_t)rr * 8192 + base, p);
            float4 im = p;
            if (mask_s[g * 128 + c]) im = ntld4(real + (size_t)rr * 8192 + base);
            #pragma unroll
            for (int cls = 0; cls < 10; cls++){
                acc[g][cls] += im.x * w40[cls]      + im.y * w40[10 + cls]
                             + im.z * w40[20 + cls] + im.w * w40[30 + cls];
            }
        }
    }
    #pragma unroll
    for (int g = 0; g < 8; g++)
        #pragma unroll
        for (int cls = 0; cls < 10; cls++){
            float v = acc[g][cls];
            for (int off = 32; off; off >>= 1) v += __shfl_down(v, off, 64);
            acc[g][cls] = v;
        }
    const int wid = t >> 6, lane = t & 63;
    if (lane == 0){
        #pragma unroll
        for (int g = 0; g < 8; g++)
            #pragma unroll
            for (int cls = 0; cls < 10; cls++) part[wid][g * 10 + cls] = acc[g][cls];
    }
    __syncthreads();
    if (t < 80) logits_s[t] = part[0][t] + part[1][t] + part[2][t] + part[3][t] + bcls[t % 10];
    __syncthreads();
    if (t < 8){
        float m = -1e30f;
        #pragma unroll
        for (int cls = 0; cls < 10; cls++) m = fmaxf(m, logits_s[t * 10 + cls]);
        float se = 0.f;
        #pragma unroll
        for (int cls = 0; cls < 10; cls++) se += expf(logits_s[t * 10 + cls] - m);
        float ls = logf(se) + m;
        #pragma unroll
        for (int cls = 0; cls < 10; cls++) out[(r0 + t) * 10 + cls] = logits_s[t * 10 + cls] - ls;
    }
}

extern "C" void kernel_launch(void* const* d_in, const int* in_sizes, int n_in,
                              void* d_out, int out_size, void* d_ws, size_t ws_size,
                              hipStream_t stream)
{
    const float* x      = (const float*)d_in[0];
    const float* e      = (const float*)d_in[1];
    const int*   src    = (const int*)d_in[2];
    const int*   dst    = (const int*)d_in[3];
    const int*   row_idx= (const int*)d_in[4];
    const int*   col_idx= (const int*)d_in[5];
    const float* real   = (const float*)d_in[6];
    const void*  mask   = d_in[7];
    const float* W1e    = (const float*)d_in[8];
    const float* b1e    = (const float*)d_in[9];
    const float* W1n    = (const float*)d_in[10];
    const float* b1n    = (const float*)d_in[11];
    const float* W2e    = (const float*)d_in[12];
    const float* b2e    = (const float*)d_in[13];
    const float* W2n    = (const float*)d_in[14];
    const float* b2n    = (const float*)d_in[15];
    const float* pe     = (const float*)d_in[16];
    const float* Wq     = (const float*)d_in[17];
    const float* Wk     = (const float*)d_in[18];
    const float* Wv     = (const float*)d_in[19];
    const float* Wref   = (const float*)d_in[20];
    const float* bref   = (const float*)d_in[21];
    const float* Wr     = (const float*)d_in[22];
    const float* Wc     = (const float*)d_in[23];
    const float* bep    = (const float*)d_in[24];
    const float* Wcls   = (const float*)d_in[25];
    const float* bcls   = (const float*)d_in[26];

    float* ws = (float*)d_ws;
    size_t off = 0;
    float* h1sum = ws + off; off += (size_t)NNODES * EHID;
    float* h2sum = ws + off; off += (size_t)NNODES * EOUTD;
    int*   cnt_i = (int*)(ws + off); off += NNODES;
    const size_t zero_floats = off;
    float* cntf  = ws + off; off += NNODES;
    int*   cursor= (int*)(ws + off); off += NNODES;
    int*   srcs  = (int*)(ws + off); off += NEDGES;
    int*   dsts  = (int*)(ws + off); off += NEDGES;
    int*   eidx  = (int*)(ws + off); off += NEDGES;
    unsigned short* xb    = (unsigned short*)(ws + off); off += (size_t)NNODES * NIN  / 2;
    unsigned short* x1b   = (unsigned short*)(ws + off); off += (size_t)NNODES * NHID / 2;
    unsigned short* x2b   = (unsigned short*)(ws + off); off += (size_t)NNODES * NOUTD / 2;
    unsigned short* W1tT  = (unsigned short*)(ws + off); off += 128 * 128 / 2;
    unsigned short* W1bT  = (unsigned short*)(ws + off); off += 128 * 64 / 2;
    unsigned short* W2tT  = (unsigned short*)(ws + off); off += 64 * 256 / 2;
    unsigned short* W2bT  = (unsigned short*)(ws + off); off += 64 * 128 / 2;
    unsigned short* W1nTb = (unsigned short*)(ws + off); off += 256 * 256 / 2;
    unsigned short* W2nTb = (unsigned short*)(ws + off); off += 256 * 320 / 2;
    unsigned short* P1b   = (unsigned short*)(ws + off); off += (size_t)NNODES * 128 / 2;
    unsigned short* P2b   = (unsigned short*)(ws + off); off += (size_t)NNODES * 64 / 2;
    float* qb    = ws + off; off += 128 * 256;
    float* kb    = ws + off; off += 128 * 256;
    float* vb    = ws + off; off += 128 * 256;
    float* distb = ws + off; off += 128 * 128;
    float* colWc = ws + off; off += 128 * 64;
    float* rowWrb= ws + off; off += (size_t)RROWS * EOUTD;
    int*   modep = (int*)(ws + off); off += 4;
    int*   blocksum = (int*)(ws + off); off += 128;
    int*   blockoff = (int*)(ws + off); off += 128;
    unsigned short* Qb;
    size_t need = (off + (size_t)NEDGES * 32) * sizeof(float);
    if (ws_size >= need) Qb = (unsigned short*)(ws + off);
    else                 Qb = (unsigned short*)((float*)d_out + (size_t)RROWS * NCLS);

    (void)hipMemsetAsync(d_ws, 0, zero_floats * sizeof(float), stream);
    k_prep<<<PREP_TOTAL, 256, 0, stream>>>(x, xb, W1e, W1tT, W1bT, W2e, W2tT, W2bT,
                                           W1n, W1nTb, W2n, W2nTb, dst, cnt_i,
                                           (const unsigned int*)mask, modep);
    k_pfx1<<<NB_PFX, 256, 0, stream>>>(cnt_i, blocksum);
    k_pfx2<<<1, 128, 0, stream>>>(blocksum, blockoff);
    k_pfx3<<<NB_PFX, 256, 0, stream>>>(cnt_i, blockoff, cursor, cntf);
    k_scatter<<<(NEDGES + 255) / 256, 256, 0, stream>>>(dst, cursor, eidx);
    k_sgather<<<(NEDGES + 255) / 256, 256, 0, stream>>>(src, dst, eidx, srcs, dsts);
    k_gemm_b16<128, 128><<<(NNODES + 63) / 64, 256, 0, stream>>>(xb, W1tT, P1b, NNODES);
    k_edge1_fused<<<NEDGES / 128, 256, 0, stream>>>(e, srcs, dsts, eidx, W1bT, b1e, P1b, W2bT, Qb, h1sum);
    k_node1_p2<<<(NNODES + 31) / 32, 256, 0, stream>>>(xb, h1sum, cntf, W1nTb, b1n, W2tT, x1b, P2b, NNODES);
    k_edge2_lite<<<NEDGES / 256, 256, 0, stream>>>(P2b, Qb, srcs, dsts, b2e, h2sum);
    k_node2<<<(NNODES + 31) / 32, 256, 0, stream>>>(x1b, h2sum, cntf, W2nTb, b2n, x2b, NNODES);
    k_attn_qkv<<<128, 256, 0, stream>>>(x1b, col_idx, pe, Wq, Wk, Wv, qb, kb, vb);
    k_attn_dist<<<128, 128, 0, stream>>>(qb, kb, distb);
    k_attn_out<<<128, 256, 0, stream>>>(distb, vb, Wref, bref, Wc, bep, colWc);
    k_rowwr<<<RROWS / 16, 256, 0, stream>>>(x2b, row_idx, Wr, rowWrb);
    k_pred8<<<RROWS / 8, 256, 0, stream>>>(rowWrb, colWc, mask, modep, real, Wcls, bcls, (float*)d_out);
}

// Round 10
// 625.028 us; speedup vs baseline: 1.0033x; 1.0033x over previous
//
#include <hip/hip_runtime.h>
#include <hip/hip_bf16.h>
#include <math.h>

#define NNODES 30000
#define NEDGES 480000
#define RROWS  8192
#define NCOLS  128
#define NIN    128
#define EIN    64
#define NHID   256
#define EHID   128
#define NOUTD  256
#define EOUTD  64
#define NCLS   10
#define NB_PFX 118   // ceil(30000/256)

typedef __attribute__((ext_vector_type(8))) unsigned short ushort8;
typedef __attribute__((ext_vector_type(8))) short bhalf8;
typedef __attribute__((ext_vector_type(4))) float floatx4;

__device__ __forceinline__ float lrelu(float v){ return v > 0.f ? v : 0.01f * v; }
__device__ __forceinline__ float4 ld4(const float* p){ return *(const float4*)p; }
__device__ __forceinline__ float4 ntld4(const float* p){
    floatx4 v = __builtin_nontemporal_load((const floatx4*)p);
    return make_float4(v.x, v.y, v.z, v.w);
}
__device__ __forceinline__ void ntst4(float* p, float4 v){
    floatx4 n = {v.x, v.y, v.z, v.w};
    __builtin_nontemporal_store(n, (floatx4*)p);
}
__device__ __forceinline__ void ntst8u(unsigned short* p, ushort8 v){
    __builtin_nontemporal_store(v, (ushort8*)p);
}
__device__ __forceinline__ unsigned short f2b(float f){
    unsigned int u = __builtin_bit_cast(unsigned int, f);
    u += 0x7fffu + ((u >> 16) & 1u);
    return (unsigned short)(u >> 16);
}
__device__ __forceinline__ float b2f(unsigned short b){
    unsigned int u = ((unsigned int)b) << 16;
    return __builtin_bit_cast(float, u);
}

// ---------------- fused prep ----------------
#define PREP_CVT_N   1875
#define PREP_W1T_B   (PREP_CVT_N)
#define PREP_W1B_B   (PREP_W1T_B + 64)
#define PREP_W2T_B   (PREP_W1B_B + 32)
#define PREP_W2B_B   (PREP_W2T_B + 64)
#define PREP_W1N_B   (PREP_W2B_B + 32)
#define PREP_W2N_B   (PREP_W1N_B + 256)
#define PREP_HIST_B  (PREP_W2N_B + 320)
#define PREP_DET_B   (PREP_HIST_B + 1875)
#define PREP_TOTAL   (PREP_DET_B + 1)

__device__ __forceinline__ void wT_region(const float* __restrict__ W, unsigned short* __restrict__ Wt,
                                          int KOFF, int KSUB, int N, int idx){
    if (idx >= N * KSUB) return;
    int n = idx / KSUB, k = idx % KSUB;
    Wt[idx] = f2b(W[(size_t)(KOFF + k) * N + n]);
}

__global__ __launch_bounds__(256) void k_prep(
    const float* __restrict__ x, unsigned short* __restrict__ xb,
    const float* __restrict__ W1e, unsigned short* __restrict__ W1tT, unsigned short* __restrict__ W1bT,
    const float* __restrict__ W2e, unsigned short* __restrict__ W2tT, unsigned short* __restrict__ W2bT,
    const float* __restrict__ W1n, unsigned short* __restrict__ W1nTb,
    const float* __restrict__ W2n, unsigned short* __restrict__ W2nTb,
    const int* __restrict__ dst, int* __restrict__ cnt_i,
    const unsigned int* __restrict__ mask, int* __restrict__ mode)
{
    const int bid = blockIdx.x, t = threadIdx.x;
    if (bid < PREP_CVT_N){
        int i = bid * 256 + t;
        float4 a = ntld4(x + (size_t)i * 8), b = ntld4(x + (size_t)i * 8 + 4);
        ushort8 o = {f2b(a.x), f2b(a.y), f2b(a.z), f2b(a.w), f2b(b.x), f2b(b.y), f2b(b.z), f2b(b.w)};
        *(ushort8*)(xb + (size_t)i * 8) = o;
    } else if (bid < PREP_W1B_B){
        wT_region(W1e, W1tT, 0, 128, 128, (bid - PREP_W1T_B) * 256 + t);
    } else if (bid < PREP_W2T_B){
        wT_region(W1e, W1bT, 128, 64, 128, (bid - PREP_W1B_B) * 256 + t);
    } else if (bid < PREP_W2B_B){
        wT_region(W2e, W2tT, 0, 256, 64, (bid - PREP_W2T_B) * 256 + t);
    } else if (bid < PREP_W1N_B){
        wT_region(W2e, W2bT, 256, 128, 64, (bid - PREP_W2B_B) * 256 + t);
    } else if (bid < PREP_W2N_B){
        wT_region(W1n, W1nTb, 0, 256, 256, (bid - PREP_W1N_B) * 256 + t);
    } else if (bid < PREP_HIST_B){
        wT_region(W2n, W2nTb, 0, 320, 256, (bid - PREP_W2N_B) * 256 + t);
    } else if (bid < PREP_DET_B){
        int i = (bid - PREP_HIST_B) * 256 + t;
        if (i < NEDGES) atomicAdd(&cnt_i[dst[i]], 1);
    } else if (t == 0){
        bool allI32 = true, allF32 = true;
        for (int i = 0; i < 64; i++){
            unsigned int v = mask[i];
            if (!(v == 0u || v == 1u)) allI32 = false;
            if (!(v == 0u || v == 0x3F800000u)) allF32 = false;
        }
        *mode = allI32 ? 0 : (allF32 ? 1 : 2);
    }
}

// ---------------- 3-stage exclusive prefix ----------------
__global__ __launch_bounds__(256) void k_pfx1(const int* __restrict__ cnt_i, int* __restrict__ blocksum){
    __shared__ int red[256];
    const int t = threadIdx.x;
    const int i = blockIdx.x * 256 + t;
    red[t] = (i < NNODES) ? cnt_i[i] : 0;
    __syncthreads();
    for (int o = 128; o; o >>= 1){ if (t < o) red[t] += red[t + o]; __syncthreads(); }
    if (t == 0) blocksum[blockIdx.x] = red[0];
}
__global__ __launch_bounds__(128) void k_pfx2(const int* __restrict__ blocksum, int* __restrict__ blockoff){
    __shared__ int s[128];
    const int t = threadIdx.x;
    int v = (t < NB_PFX) ? blocksum[t] : 0;
    s[t] = v;
    __syncthreads();
    for (int o = 1; o < 128; o <<= 1){
        int add = (t >= o) ? s[t - o] : 0;
        __syncthreads();
        s[t] += add;
        __syncthreads();
    }
    if (t < NB_PFX) blockoff[t] = s[t] - v;
}
__global__ __launch_bounds__(256) void k_pfx3(const int* __restrict__ cnt_i, const int* __restrict__ blockoff,
                                              int* __restrict__ cursor, float* __restrict__ cntf){
    __shared__ int s[256];
    const int t = threadIdx.x;
    const int i = blockIdx.x * 256 + t;
    int v = (i < NNODES) ? cnt_i[i] : 0;
    s[t] = v;
    __syncthreads();
    for (int o = 1; o < 256; o <<= 1){
        int add = (t >= o) ? s[t - o] : 0;
        __syncthreads();
        s[t] += add;
        __syncthreads();
    }
    if (i < NNODES){
        cursor[i] = s[t] - v + blockoff[blockIdx.x];
        cntf[i] = (float)v;
    }
}

__global__ void k_scatter(const int* __restrict__ dst, int* __restrict__ cursor, int* __restrict__ eidx){
    int i = blockIdx.x * 256 + threadIdx.x;
    if (i >= NEDGES) return;
    int pos = atomicAdd(&cursor[dst[i]], 1);
    eidx[pos] = i;
}

// ---------------- gather sorted src/dst + e rows (bf16, streaming) ----------------
// 64 edges per block, 4 threads per edge. No barriers: pure-MLP gather.
__global__ __launch_bounds__(256) void k_sgather(
    const int* __restrict__ src, const int* __restrict__ dst, const int* __restrict__ eidx,
    const float* __restrict__ e,
    int* __restrict__ srcs, int* __restrict__ dsts, unsigned short* __restrict__ es)
{
    const int t = threadIdx.x;
    const int r = t >> 2, q = t & 3;
    const int p = blockIdx.x * 64 + r;
    const int i = eidx[p];
    if (q == 0){ srcs[p] = src[i]; dsts[p] = dst[i]; }
    const float* ep = e + (size_t)i * 64 + q * 16;
    float4 f0 = ntld4(ep), f1 = ntld4(ep + 4), f2 = ntld4(ep + 8), f3 = ntld4(ep + 12);
    ushort8 u0 = {f2b(f0.x), f2b(f0.y), f2b(f0.z), f2b(f0.w), f2b(f1.x), f2b(f1.y), f2b(f1.z), f2b(f1.w)};
    ushort8 u1 = {f2b(f2.x), f2b(f2.y), f2b(f2.z), f2b(f2.w), f2b(f3.x), f2b(f3.y), f2b(f3.z), f2b(f3.w)};
    ntst8u(es + (size_t)p * 64 + q * 16,     u0);
    ntst8u(es + (size_t)p * 64 + q * 16 + 8, u1);
}

// ---------------- small GEMM: out_bf16[M,N] = Ab[M,K] @ Wt[N,K] ----------------
template<int K, int N>
__global__ __launch_bounds__(256) void k_gemm_b16(
    const unsigned short* __restrict__ Ab, const unsigned short* __restrict__ Wt,
    unsigned short* __restrict__ outb, int M)
{
    __shared__ unsigned short At[64][K + 8];
    const int t = threadIdx.x;
    const int r0 = blockIdx.x * 64;
    {
        const int r = t >> 2, q = t & 3;
        const int row = r0 + r;
        const bool valid = row < M;
        const unsigned short* a = Ab + (size_t)(valid ? row : 0) * K;
        for (int kk = q * (K / 4); kk < (q + 1) * (K / 4); kk += 8){
            ushort8 u;
            if (valid) u = *(const ushort8*)(a + kk);
            else       u = (ushort8){0,0,0,0,0,0,0,0};
            *(ushort8*)&At[r][kk] = u;
        }
    }
    __syncthreads();
    const int lane = t & 63, w = t >> 6;
    const int fr = lane & 15, fq = lane >> 4;
    constexpr int NF = N / 16;
    floatx4 acc[NF] = {};
    #pragma unroll
    for (int ks = 0; ks < K / 32; ks++){
        const int k = ks * 32 + fq * 8;
        bhalf8 a = *(bhalf8*)&At[w * 16 + fr][k];
        #pragma unroll
        for (int n = 0; n < NF; n++){
            bhalf8 b = *(const bhalf8*)(Wt + (size_t)(n * 16 + fr) * K + k);
            acc[n] = __builtin_amdgcn_mfma_f32_16x16x32_bf16(a, b, acc[n], 0, 0, 0);
        }
    }
    #pragma unroll
    for (int n = 0; n < NF; n++){
        const int col = n * 16 + fr;
        #pragma unroll
        for (int rr = 0; rr < 4; rr++){
            const int row = r0 + w * 16 + fq * 4 + rr;
            if (row < M) outb[(size_t)row * N + col] = f2b(acc[n][rr]);
        }
    }
}

// ---------------- fused edge layer 1 (round-7 structure, coalesced es input) ----------------
__global__ __launch_bounds__(256) void k_edge1_fused(
    const unsigned short* __restrict__ es,
    const int* __restrict__ srcs, const int* __restrict__ dsts,
    const unsigned short* __restrict__ W1bT, const float* __restrict__ b1e,
    const unsigned short* __restrict__ P1b, const unsigned short* __restrict__ W2bT,
    unsigned short* __restrict__ Qb, float* __restrict__ hsum)
{
    __shared__ unsigned short Cb[64][136];
    __shared__ unsigned short P1s[64][136];
    __shared__ int dstS[64];
    const int t = threadIdx.x;
    const int p0 = blockIdx.x * 64;
    const int r = t >> 2, q = t & 3;
    // phase A: coalesced es read -> Cb; P1 tile -> P1s
    {
        const int p = p0 + r;
        if (q == 0) dstS[r] = dsts[p];
        const int srow = srcs[p];
        const unsigned short* pp = P1b + (size_t)srow * 128 + q * 32;
        *(ushort8*)&P1s[r][q * 32]      = *(const ushort8*)pp;
        *(ushort8*)&P1s[r][q * 32 + 8]  = *(const ushort8*)(pp + 8);
        *(ushort8*)&P1s[r][q * 32 + 16] = *(const ushort8*)(pp + 16);
        *(ushort8*)&P1s[r][q * 32 + 24] = *(const ushort8*)(pp + 24);
        const unsigned short* ep = es + (size_t)p * 64 + q * 16;
        *(ushort8*)&Cb[r][q * 16]     = *(const ushort8*)ep;
        *(ushort8*)&Cb[r][q * 16 + 8] = *(const ushort8*)(ep + 8);
    }
    __syncthreads();
    const int lane = t & 63, w = t >> 6;
    const int wm = w >> 1, wn = w & 1;
    const int fr = lane & 15, fq = lane >> 4;
    // phase B: acc1 = e_tile @ W1bT
    floatx4 acc1[2][4] = {};
    #pragma unroll
    for (int ks = 0; ks < 2; ks++){
        const int k = ks * 32 + fq * 8;
        bhalf8 a0 = *(bhalf8*)&Cb[wm * 32 + fr][k];
        bhalf8 a1 = *(bhalf8*)&Cb[wm * 32 + 16 + fr][k];
        #pragma unroll
        for (int n = 0; n < 4; n++){
            const int col = wn * 64 + n * 16 + fr;
            bhalf8 b = *(const bhalf8*)(W1bT + (size_t)col * 64 + k);
            acc1[0][n] = __builtin_amdgcn_mfma_f32_16x16x32_bf16(a0, b, acc1[0][n], 0, 0, 0);
            acc1[1][n] = __builtin_amdgcn_mfma_f32_16x16x32_bf16(a1, b, acc1[1][n], 0, 0, 0);
        }
    }
    __syncthreads();
    // phase C: e1 = leaky(acc1 + P1s + b1e) -> Cb
    #pragma unroll
    for (int m = 0; m < 2; m++){
        #pragma unroll
        for (int n = 0; n < 4; n++){
            const int col = wn * 64 + n * 16 + fr;
            const float bv = b1e[col];
            #pragma unroll
            for (int rr = 0; rr < 4; rr++){
                const int row = wm * 32 + m * 16 + fq * 4 + rr;
                const float pv = b2f(P1s[row][col]);
                Cb[row][col] = f2b(lrelu(acc1[m][n][rr] + pv + bv));
            }
        }
    }
    __syncthreads();
    // phase D: Q = e1 @ W2bT -> stage into P1s
    {
        floatx4 acc2[4] = {};
        #pragma unroll
        for (int ks = 0; ks < 4; ks++){
            const int k = ks * 32 + fq * 8;
            bhalf8 a = *(bhalf8*)&Cb[w * 16 + fr][k];
            #pragma unroll
            for (int n = 0; n < 4; n++){
                bhalf8 b = *(const bhalf8*)(W2bT + (size_t)(n * 16 + fr) * 128 + k);
                acc2[n] = __builtin_amdgcn_mfma_f32_16x16x32_bf16(a, b, acc2[n], 0, 0, 0);
            }
        }
        #pragma unroll
        for (int n = 0; n < 4; n++){
            const int col = n * 16 + fr;
            #pragma unroll
            for (int rr = 0; rr < 4; rr++){
                const int row = w * 16 + fq * 4 + rr;
                P1s[row][col] = f2b(acc2[n][rr]);
            }
        }
    }
    __syncthreads();
    // coalesced Q store
    {
        unsigned short* op = Qb + (size_t)(p0 + r) * 64 + q * 16;
        ntst8u(op,     *(ushort8*)&P1s[r][q * 16]);
        ntst8u(op + 8, *(ushort8*)&P1s[r][q * 16 + 8]);
    }
    // phase E: run-reduced scatter-add of e1 to h1sum
    {
        const int col = t & 127, half = t >> 7;
        const int rbase = half * 32;
        float s = 0.f;
        int prev = dstS[rbase];
        #pragma unroll 4
        for (int rr = 0; rr < 32; rr++){
            const int rw2 = rbase + rr;
            const int d = dstS[rw2];
            if (d != prev){
                atomicAdd(&hsum[(size_t)prev * EHID + col], s);
                s = 0.f; prev = d;
            }
            s += b2f(Cb[rw2][col]);
        }
        atomicAdd(&hsum[(size_t)prev * EHID + col], s);
    }
}

// ---------------- edge layer 2 (lite) ----------------
__global__ __launch_bounds__(256) void k_edge2_lite(
    const unsigned short* __restrict__ P2b, const unsigned short* __restrict__ Qb,
    const int* __restrict__ srcs, const int* __restrict__ dsts,
    const float* __restrict__ b2e, float* __restrict__ hsum)
{
    const int t = threadIdx.x;
    const int lane = t & 63, w = t >> 6;
    const int p0 = blockIdx.x * 256 + w * 64;
    const float bias = b2e[lane];
    float s = 0.f;
    int prev = dsts[p0];
    #pragma unroll 4
    for (int i = 0; i < 64; i++){
        const int p = p0 + i;
        const int d = dsts[p];
        if (d != prev){
            atomicAdd(&hsum[(size_t)prev * EOUTD + lane], s);
            s = 0.f; prev = d;
        }
        const float q  = b2f(__builtin_nontemporal_load(&Qb[(size_t)p * 64 + lane]));
        const float pv = b2f(P2b[(size_t)srcs[p] * 64 + lane]);
        s += lrelu(pv + q + bias);
    }
    atomicAdd(&hsum[(size_t)prev * EOUTD + lane], s);
}

// ---------------- node1 + fused P2 ----------------
__global__ __launch_bounds__(256) void k_node1_p2(
    const unsigned short* __restrict__ A1b, const float* __restrict__ hsum,
    const float* __restrict__ cntf,
    const unsigned short* __restrict__ Wt, const float* __restrict__ bias,
    const unsigned short* __restrict__ W2tT,
    unsigned short* __restrict__ x1b, unsigned short* __restrict__ P2b, int M)
{
    constexpr int K = 256;
    __shared__ unsigned short At[32][K + 8];
    const int t = threadIdx.x;
    const int r0 = blockIdx.x * 32;
    {
        const int r = t >> 3, q = t & 7;
        const int row = r0 + r;
        const bool valid = row < M;
        float rinv = 0.f;
        const unsigned short* a1 = A1b;
        const float* a2 = hsum;
        if (valid){
            rinv = 1.f / fmaxf(cntf[row], 1.f);
            a1 = A1b  + (size_t)row * NIN;
            a2 = hsum + (size_t)row * EHID;
        }
        for (int kk = q * 32; kk < q * 32 + 32; kk += 8){
            ushort8 u;
            if (!valid){
                u = (ushort8){0,0,0,0,0,0,0,0};
            } else if (kk < NIN){
                u = *(const ushort8*)(a1 + kk);
            } else {
                float4 g0 = ld4(a2 + (kk - NIN)), g1 = ld4(a2 + (kk - NIN) + 4);
                u = (ushort8){f2b(g0.x*rinv), f2b(g0.y*rinv), f2b(g0.z*rinv), f2b(g0.w*rinv),
                              f2b(g1.x*rinv), f2b(g1.y*rinv), f2b(g1.z*rinv), f2b(g1.w*rinv)};
            }
            *(ushort8*)&At[r][kk] = u;
        }
    }
    __syncthreads();
    const int lane = t & 63, w = t >> 6;
    const int wm = w >> 1, wn = w & 1;
    const int fr = lane & 15, fq = lane >> 4;
    floatx4 acc[8] = {};
    #pragma unroll
    for (int ks = 0; ks < 8; ks++){
        const int k = ks * 32 + fq * 8;
        bhalf8 a = *(bhalf8*)&At[wm * 16 + fr][k];
        #pragma unroll
        for (int n = 0; n < 8; n++){
            const int col = wn * 128 + n * 16 + fr;
            bhalf8 b = *(const bhalf8*)(Wt + (size_t)col * K + k);
            acc[n] = __builtin_amdgcn_mfma_f32_16x16x32_bf16(a, b, acc[n], 0, 0, 0);
        }
    }
    __syncthreads();
    #pragma unroll
    for (int n = 0; n < 8; n++){
        const int col = wn * 128 + n * 16 + fr;
        const float bv = bias[col];
        #pragma unroll
        for (int rr = 0; rr < 4; rr++){
            const int row = r0 + wm * 16 + fq * 4 + rr;
            unsigned short ob = f2b(lrelu(acc[n][rr] + bv));
            At[wm * 16 + fq * 4 + rr][col] = ob;
            if (row < M) x1b[(size_t)row * 256 + col] = ob;
        }
    }
    __syncthreads();
    {
        floatx4 acc2[2] = {};
        #pragma unroll
        for (int ks = 0; ks < 8; ks++){
            const int k = ks * 32 + fq * 8;
            bhalf8 a = *(bhalf8*)&At[wm * 16 + fr][k];
            #pragma unroll
            for (int n = 0; n < 2; n++){
                const int col = wn * 32 + n * 16 + fr;
                bhalf8 b = *(const bhalf8*)(W2tT + (size_t)col * 256 + k);
                acc2[n] = __builtin_amdgcn_mfma_f32_16x16x32_bf16(a, b, acc2[n], 0, 0, 0);
            }
        }
        #pragma unroll
        for (int n = 0; n < 2; n++){
            const int col = wn * 32 + n * 16 + fr;
            #pragma unroll
            for (int rr = 0; rr < 4; rr++){
                const int row = r0 + wm * 16 + fq * 4 + rr;
                if (row < M) P2b[(size_t)row * 64 + col] = f2b(acc2[n][rr]);
            }
        }
    }
}

// ---------------- node2 (bf16-out only) ----------------
__global__ __launch_bounds__(256) void k_node2(
    const unsigned short* __restrict__ A1b, const float* __restrict__ hsum,
    const float* __restrict__ cntf,
    const unsigned short* __restrict__ Wt, const float* __restrict__ bias,
    unsigned short* __restrict__ outb, int M)
{
    constexpr int K = 320;
    __shared__ unsigned short At[32][K + 8];
    const int t = threadIdx.x;
    const int r0 = blockIdx.x * 32;
    {
        const int r = t >> 3, q = t & 7;
        const int row = r0 + r;
        const bool valid = row < M;
        float rinv = 0.f;
        const unsigned short* a1 = A1b;
        const float* a2 = hsum;
        if (valid){
            rinv = 1.f / fmaxf(cntf[row], 1.f);
            a1 = A1b  + (size_t)row * NHID;
            a2 = hsum + (size_t)row * EOUTD;
        }
        for (int kk = q * 40; kk < q * 40 + 40; kk += 8){
            ushort8 u;
            if (!valid){
                u = (ushort8){0,0,0,0,0,0,0,0};
            } else if (kk < NHID){
                u = *(const ushort8*)(a1 + kk);
            } else {
                float4 g0 = ld4(a2 + (kk - NHID)), g1 = ld4(a2 + (kk - NHID) + 4);
                u = (ushort8){f2b(g0.x*rinv), f2b(g0.y*rinv), f2b(g0.z*rinv), f2b(g0.w*rinv),
                              f2b(g1.x*rinv), f2b(g1.y*rinv), f2b(g1.z*rinv), f2b(g1.w*rinv)};
            }
            *(ushort8*)&At[r][kk] = u;
        }
    }
    __syncthreads();
    const int lane = t & 63, w = t >> 6;
    const int wm = w >> 1, wn = w & 1;
    const int fr = lane & 15, fq = lane >> 4;
    floatx4 acc[8] = {};
    #pragma unroll
    for (int ks = 0; ks < 10; ks++){
        const int k = ks * 32 + fq * 8;
        bhalf8 a = *(bhalf8*)&At[wm * 16 + fr][k];
        #pragma unroll
        for (int n = 0; n < 8; n++){
            const int col = wn * 128 + n * 16 + fr;
            bhalf8 b = *(const bhalf8*)(Wt + (size_t)col * K + k);
            acc[n] = __builtin_amdgcn_mfma_f32_16x16x32_bf16(a, b, acc[n], 0, 0, 0);
        }
    }
    #pragma unroll
    for (int n = 0; n < 8; n++){
        const int col = wn * 128 + n * 16 + fr;
        const float bv = bias[col];
        #pragma unroll
        for (int rr = 0; rr < 4; rr++){
            const int row = r0 + wm * 16 + fq * 4 + rr;
            if (row < M) outb[(size_t)row * 256 + col] = f2b(lrelu(acc[n][rr] + bv));
        }
    }
}

// ---------------- attention: q,k,v (x1 bf16) ----------------
__global__ __launch_bounds__(256) void k_attn_qkv(
    const unsigned short* __restrict__ x1b, const int* __restrict__ col_idx,
    const float* __restrict__ pe,
    const float* __restrict__ Wq, const float* __restrict__ Wk, const float* __restrict__ Wv,
    float* __restrict__ qo, float* __restrict__ ko, float* __restrict__ vo)
{
    __shared__ float c[256];
    const int i = blockIdx.x, t = threadIdx.x;
    const int col = col_idx[i];
    c[t] = b2f(x1b[(size_t)col * 256 + t]) + pe[i * 256 + t];
    __syncthreads();
    float aq = 0.f, ak = 0.f, av = 0.f;
    #pragma unroll 4
    for (int kk = 0; kk < 256; kk++){
        float cv = c[kk];
        aq += cv * Wq[kk * 256 + t];
        ak += cv * Wk[kk * 256 + t];
        av += cv * Wv[kk * 256 + t];
    }
    qo[i * 256 + t] = aq; ko[i * 256 + t] = ak; vo[i * 256 + t] = av;
}

// ---------------- attention: dist ----------------
__global__ __launch_bounds__(128) void k_attn_dist(
    const float* __restrict__ q, const float* __restrict__ k, float* __restrict__ dist)
{
    __shared__ float qr[256];
    __shared__ float red[128];
    const int i = blockIdx.x, t = threadIdx.x;
    qr[t] = q[i * 256 + t]; qr[t + 128] = q[i * 256 + t + 128];
    __syncthreads();
    float s = 0.f;
    #pragma unroll 4
    for (int kk = 0; kk < 256; kk++) s += qr[kk] * k[t * 256 + kk];
    s *= 0.0625f;
    red[t] = s; __syncthreads();
    for (int off = 64; off; off >>= 1){ if (t < off) red[t] = fmaxf(red[t], red[t + off]); __syncthreads(); }
    float m = red[0]; __syncthreads();
    float ex = expf(s - m);
    red[t] = ex; __syncthreads();
    for (int off = 64; off; off >>= 1){ if (t < off) red[t] += red[t + off]; __syncthreads(); }
    dist[i * 128 + t] = ex / red[0];
}

// ---------------- attention tail ----------------
__global__ __launch_bounds__(256) void k_attn_out(
    const float* __restrict__ dist, const float* __restrict__ v,
    const float* __restrict__ Wref, const float* __restrict__ bref,
    const float* __restrict__ Wc, const float* __restrict__ bep,
    float* __restrict__ colWc)
{
    __shared__ float dr[128];
    __shared__ float c2[256];
    __shared__ float nc[256];
    const int i = blockIdx.x, t = threadIdx.x;
    if (t < 128) dr[t] = dist[i * 128 + t];
    __syncthreads();
    float s = 0.f;
    #pragma unroll 4
    for (int j = 0; j < 128; j++) s += dr[j] * v[j * 256 + t];
    c2[t] = 2.f * s;
    __syncthreads();
    float a = 0.f;
    #pragma unroll 4
    for (int kk = 0; kk < 256; kk++) a += c2[kk] * Wref[kk * 256 + t];
    a += bref[t];
    nc[t] = 1.f / (1.f + expf(-a));
    __syncthreads();
    if (t < 64){
        float o = 0.f;
        #pragma unroll 4
        for (int kk = 0; kk < 256; kk++) o += nc[kk] * Wc[kk * 64 + t];
        colWc[i * 64 + t] = o + bep[t];
    }
}

// ---------------- rowWr = x2b[row_idx] @ Wr ----------------
__global__ __launch_bounds__(256) void k_rowwr(
    const unsigned short* __restrict__ x2b, const int* __restrict__ row_idx,
    const float* __restrict__ Wr, float* __restrict__ rw)
{
    __shared__ unsigned short A[16][264];
    const int t = threadIdx.x;
    const int r0 = blockIdx.x * 16;
    const int rl = t >> 4, cg = t & 15;
    const int ridx = row_idx[r0 + rl];
    const unsigned short* ar = x2b + (size_t)ridx * 256;
    for (int i = cg; i < 32; i += 16) *(ushort8*)&A[rl][i * 8] = *(const ushort8*)(ar + i * 8);
    __syncthreads();
    float acc[4] = {0.f, 0.f, 0.f, 0.f};
    #pragma unroll 4
    for (int kk = 0; kk < 256; kk++){
        float4 w = ld4(Wr + (size_t)kk * 64 + cg * 4);
        float a = b2f(A[rl][kk]);
        acc[0] += a * w.x; acc[1] += a * w.y; acc[2] += a * w.z; acc[3] += a * w.w;
    }
    *(float4*)(rw + (size_t)(r0 + rl) * 64 + cg * 4) = make_float4(acc[0], acc[1], acc[2], acc[3]);
}

// ---------------- fused: pred -> d_out (nt), imputation, classifier, log_softmax ----------------
__global__ __launch_bounds__(256) void k_pred8(
    const float* __restrict__ rowWr, const float* __restrict__ colWc,
    const void* __restrict__ maskp, const int* __restrict__ modep,
    const float* __restrict__ real, const float* __restrict__ Wcls, const float* __restrict__ bcls,
    float* __restrict__ out)
{
    __shared__ float colWc_s[8192];
    __shared__ float rowWr_s[8 * 64];
    __shared__ unsigned char mask_s[8 * 128];
    __shared__ float part[4][80];
    __shared__ float logits_s[80];
    const int t  = threadIdx.x;
    const int r0 = blockIdx.x * 8;
    const int mode = *modep;
    for (int idx = t; idx < 2048; idx += 256)
        *(float4*)&colWc_s[idx * 4] = ld4(colWc + idx * 4);
    for (int idx = t; idx < 128; idx += 256)
        *(float4*)&rowWr_s[idx * 4] = ld4(rowWr + (size_t)r0 * 64 + idx * 4);
    for (int idx = t; idx < 1024; idx += 256){
        const int g = idx >> 7, c = idx & 127;
        const int gi = (r0 + g) * 128 + c;
        bool m;
        if (mode == 2)      m = ((const unsigned char*)maskp)[gi] != 0;
        else if (mode == 0) m = ((const int*)maskp)[gi] != 0;
        else                m = ((const float*)maskp)[gi] != 0.f;
        mask_s[idx] = m ? 1 : 0;
    }
    __syncthreads();

    float acc[8][10];
    #pragma unroll
    for (int g = 0; g < 8; g++)
        #pragma unroll
        for (int c = 0; c < 10; c++) acc[g][c] = 0.f;
    float* pred = out + RROWS * NCLS;

    #pragma unroll 1
    for (int i = 0; i < 8; i++){
        const int e4   = i * 256 + t;
        const int base = e4 * 4;
        const int c = base >> 6;
        const int j = base & 63;
        float4 cw = ld4(&colWc_s[c * 64 + j]);
        float w40[40];
        #pragma unroll
        for (int u = 0; u < 10; u++){
            float4 wv = ld4(Wcls + (size_t)base * 10 + u * 4);
            w40[u*4+0] = wv.x; w40[u*4+1] = wv.y; w40[u*4+2] = wv.z; w40[u*4+3] = wv.w;
        }
        #pragma unroll
        for (int g = 0; g < 8; g++){
            const int rr = r0 + g;
            float4 rwv = ld4(&rowWr_s[g * 64 + j]);
            float4 p;
            p.x = lrelu(rwv.x + cw.x); p.y = lrelu(rwv.y + cw.y);
            p.z = lrelu(rwv.z + cw.z); p.w = lrelu(rwv.w + cw.w);
            ntst4(pred + (size_t)rr * 8192 + base, p);
            float4 im = p;
            if (mask_s[g * 128 + c]) im = ntld4(real + (size_t)rr * 8192 + base);
            #pragma unroll
            for (int cls = 0; cls < 10; cls++){
                acc[g][cls] += im.x * w40[cls]      + im.y * w40[10 + cls]
                             + im.z * w40[20 + cls] + im.w * w40[30 + cls];
            }
        }
    }
    #pragma unroll
    for (int g = 0; g < 8; g++)
        #pragma unroll
        for (int cls = 0; cls < 10; cls++){
            float v = acc[g][cls];
            for (int off = 32; off; off >>= 1) v += __shfl_down(v, off, 64);
            acc[g][cls] = v;
        }
    const int wid = t >> 6, lane = t & 63;
    if (lane == 0){
        #pragma unroll
        for (int g = 0; g < 8; g++)
            #pragma unroll
            for (int cls = 0; cls < 10; cls++) part[wid][g * 10 + cls] = acc[g][cls];
    }
    __syncthreads();
    if (t < 80) logits_s[t] = part[0][t] + part[1][t] + part[2][t] + part[3][t] + bcls[t % 10];
    __syncthreads();
    if (t < 8){
        float m = -1e30f;
        #pragma unroll
        for (int cls = 0; cls < 10; cls++) m = fmaxf(m, logits_s[t * 10 + cls]);
        float se = 0.f;
        #pragma unroll
        for (int cls = 0; cls < 10; cls++) se += expf(logits_s[t * 10 + cls] - m);
        float ls = logf(se) + m;
        #pragma unroll
        for (int cls = 0; cls < 10; cls++) out[(r0 + t) * 10 + cls] = logits_s[t * 10 + cls] - ls;
    }
}

extern "C" void kernel_launch(void* const* d_in, const int* in_sizes, int n_in,
                              void* d_out, int out_size, void* d_ws, size_t ws_size,
                              hipStream_t stream)
{
    const float* x      = (const float*)d_in[0];
    const float* e      = (const float*)d_in[1];
    const int*   src    = (const int*)d_in[2];
    const int*   dst    = (const int*)d_in[3];
    const int*   row_idx= (const int*)d_in[4];
    const int*   col_idx= (const int*)d_in[5];
    const float* real   = (const float*)d_in[6];
    const void*  mask   = d_in[7];
    const float* W1e    = (const float*)d_in[8];
    const float* b1e    = (const float*)d_in[9];
    const float* W1n    = (const float*)d_in[10];
    const float* b1n    = (const float*)d_in[11];
    const float* W2e    = (const float*)d_in[12];
    const float* b2e    = (const float*)d_in[13];
    const float* W2n    = (const float*)d_in[14];
    const float* b2n    = (const float*)d_in[15];
    const float* pe     = (const float*)d_in[16];
    const float* Wq     = (const float*)d_in[17];
    const float* Wk     = (const float*)d_in[18];
    const float* Wv     = (const float*)d_in[19];
    const float* Wref   = (const float*)d_in[20];
    const float* bref   = (const float*)d_in[21];
    const float* Wr     = (const float*)d_in[22];
    const float* Wc     = (const float*)d_in[23];
    const float* bep    = (const float*)d_in[24];
    const float* Wcls   = (const float*)d_in[25];
    const float* bcls   = (const float*)d_in[26];

    float* ws = (float*)d_ws;
    size_t off = 0;
    float* h1sum = ws + off; off += (size_t)NNODES * EHID;
    float* h2sum = ws + off; off += (size_t)NNODES * EOUTD;
    int*   cnt_i = (int*)(ws + off); off += NNODES;
    const size_t zero_floats = off;
    float* cntf  = ws + off; off += NNODES;
    int*   cursor= (int*)(ws + off); off += NNODES;
    int*   srcs  = (int*)(ws + off); off += NEDGES;
    int*   dsts  = (int*)(ws + off); off += NEDGES;
    int*   eidx  = (int*)(ws + off); off += NEDGES;
    unsigned short* xb    = (unsigned short*)(ws + off); off += (size_t)NNODES * NIN  / 2;
    unsigned short* x1b   = (unsigned short*)(ws + off); off += (size_t)NNODES * NHID / 2;
    unsigned short* x2b   = (unsigned short*)(ws + off); off += (size_t)NNODES * NOUTD / 2;
    unsigned short* W1tT  = (unsigned short*)(ws + off); off += 128 * 128 / 2;
    unsigned short* W1bT  = (unsigned short*)(ws + off); off += 128 * 64 / 2;
    unsigned short* W2tT  = (unsigned short*)(ws + off); off += 64 * 256 / 2;
    unsigned short* W2bT  = (unsigned short*)(ws + off); off += 64 * 128 / 2;
    unsigned short* W1nTb = (unsigned short*)(ws + off); off += 256 * 256 / 2;
    unsigned short* W2nTb = (unsigned short*)(ws + off); off += 256 * 320 / 2;
    unsigned short* P1b   = (unsigned short*)(ws + off); off += (size_t)NNODES * 128 / 2;
    unsigned short* P2b   = (unsigned short*)(ws + off); off += (size_t)NNODES * 64 / 2;
    float* qb    = ws + off; off += 128 * 256;
    float* kb    = ws + off; off += 128 * 256;
    float* vb    = ws + off; off += 128 * 256;
    float* distb = ws + off; off += 128 * 128;
    float* colWc = ws + off; off += 128 * 64;
    float* rowWrb= ws + off; off += (size_t)RROWS * EOUTD;
    int*   modep = (int*)(ws + off); off += 4;
    int*   blocksum = (int*)(ws + off); off += 128;
    int*   blockoff = (int*)(ws + off); off += 128;
    // es (sorted bf16 e rows) and Qb: use ws if they fit, else borrow disjoint
    // slices of d_out's pred region (both consumed before k_pred8 writes pred).
    unsigned short* es;
    unsigned short* Qb;
    {
        size_t need_es = (off + (size_t)NEDGES * 32) * sizeof(float);
        if (ws_size >= need_es){ es = (unsigned short*)(ws + off); off += (size_t)NEDGES * 32; }
        else                     es = (unsigned short*)((float*)d_out + (size_t)RROWS * NCLS + 20000000);
        size_t need_q = (off + (size_t)NEDGES * 32) * sizeof(float);
        if (ws_size >= need_q){ Qb = (unsigned short*)(ws + off); off += (size_t)NEDGES * 32; }
        else                    Qb = (unsigned short*)((float*)d_out + (size_t)RROWS * NCLS);
    }

    (void)hipMemsetAsync(d_ws, 0, zero_floats * sizeof(float), stream);
    k_prep<<<PREP_TOTAL, 256, 0, stream>>>(x, xb, W1e, W1tT, W1bT, W2e, W2tT, W2bT,
                                           W1n, W1nTb, W2n, W2nTb, dst, cnt_i,
                                           (const unsigned int*)mask, modep);
    k_pfx1<<<NB_PFX, 256, 0, stream>>>(cnt_i, blocksum);
    k_pfx2<<<1, 128, 0, stream>>>(blocksum, blockoff);
    k_pfx3<<<NB_PFX, 256, 0, stream>>>(cnt_i, blockoff, cursor, cntf);
    k_scatter<<<(NEDGES + 255) / 256, 256, 0, stream>>>(dst, cursor, eidx);
    k_sgather<<<NEDGES / 64, 256, 0, stream>>>(src, dst, eidx, e, srcs, dsts, es);
    k_gemm_b16<128, 128><<<(NNODES + 63) / 64, 256, 0, stream>>>(xb, W1tT, P1b, NNODES);
    k_edge1_fused<<<NEDGES / 64, 256, 0, stream>>>(es, srcs, dsts, W1bT, b1e, P1b, W2bT, Qb, h1sum);
    k_node1_p2<<<(NNODES + 31) / 32, 256, 0, stream>>>(xb, h1sum, cntf, W1nTb, b1n, W2tT, x1b, P2b, NNODES);
    k_edge2_lite<<<NEDGES / 256, 256, 0, stream>>>(P2b, Qb, srcs, dsts, b2e, h2sum);
    k_node2<<<(NNODES + 31) / 32, 256, 0, stream>>>(x1b, h2sum, cntf, W2nTb, b2n, x2b, NNODES);
    k_attn_qkv<<<128, 256, 0, stream>>>(x1b, col_idx, pe, Wq, Wk, Wv, qb, kb, vb);
    k_attn_dist<<<128, 128, 0, stream>>>(qb, kb, distb);
    k_attn_out<<<128, 256, 0, stream>>>(distb, vb, Wref, bref, Wc, bep, colWc);
    k_rowwr<<<RROWS / 16, 256, 0, stream>>>(x2b, row_idx, Wr, rowWrb);
    k_pred8<<<RROWS / 8, 256, 0, stream>>>(rowWrb, colWc, mask, modep, real, Wcls, bcls, (float*)d_out);
}

// Round 11
// 599.163 us; speedup vs baseline: 1.0466x; 1.0432x over previous
//
#include <hip/hip_runtime.h>
#include <hip/hip_bf16.h>
#include <math.h>

#define NNODES 30000
#define NEDGES 480000
#define RROWS  8192
#define NCOLS  128
#define NIN    128
#define EIN    64
#define NHID   256
#define EHID   128
#define NOUTD  256
#define EOUTD  64
#define NCLS   10
#define NB_PFX 118   // ceil(30000/256)

typedef __attribute__((ext_vector_type(8))) unsigned short ushort8;
typedef __attribute__((ext_vector_type(8))) short bhalf8;
typedef __attribute__((ext_vector_type(4))) float floatx4;

__device__ __forceinline__ float lrelu(float v){ return v > 0.f ? v : 0.01f * v; }
__device__ __forceinline__ float4 ld4(const float* p){ return *(const float4*)p; }
__device__ __forceinline__ float4 ntld4(const float* p){
    floatx4 v = __builtin_nontemporal_load((const floatx4*)p);
    return make_float4(v.x, v.y, v.z, v.w);
}
__device__ __forceinline__ void ntst4(float* p, float4 v){
    floatx4 n = {v.x, v.y, v.z, v.w};
    __builtin_nontemporal_store(n, (floatx4*)p);
}
__device__ __forceinline__ void ntst8u(unsigned short* p, ushort8 v){
    __builtin_nontemporal_store(v, (ushort8*)p);
}
__device__ __forceinline__ unsigned short f2b(float f){
    unsigned int u = __builtin_bit_cast(unsigned int, f);
    u += 0x7fffu + ((u >> 16) & 1u);
    return (unsigned short)(u >> 16);
}
__device__ __forceinline__ float b2f(unsigned short b){
    unsigned int u = ((unsigned int)b) << 16;
    return __builtin_bit_cast(float, u);
}

// ---------------- fused prep ----------------
#define PREP_CVT_N   1875
#define PREP_W1T_B   (PREP_CVT_N)
#define PREP_W1B_B   (PREP_W1T_B + 64)
#define PREP_W2T_B   (PREP_W1B_B + 32)
#define PREP_W2B_B   (PREP_W2T_B + 64)
#define PREP_W1N_B   (PREP_W2B_B + 32)
#define PREP_W2N_B   (PREP_W1N_B + 256)
#define PREP_HIST_B  (PREP_W2N_B + 320)
#define PREP_DET_B   (PREP_HIST_B + 1875)
#define PREP_TOTAL   (PREP_DET_B + 1)

__device__ __forceinline__ void wT_region(const float* __restrict__ W, unsigned short* __restrict__ Wt,
                                          int KOFF, int KSUB, int N, int idx){
    if (idx >= N * KSUB) return;
    int n = idx / KSUB, k = idx % KSUB;
    Wt[idx] = f2b(W[(size_t)(KOFF + k) * N + n]);
}

__global__ __launch_bounds__(256) void k_prep(
    const float* __restrict__ x, unsigned short* __restrict__ xb,
    const float* __restrict__ W1e, unsigned short* __restrict__ W1tT, unsigned short* __restrict__ W1bT,
    const float* __restrict__ W2e, unsigned short* __restrict__ W2tT, unsigned short* __restrict__ W2bT,
    const float* __restrict__ W1n, unsigned short* __restrict__ W1nTb,
    const float* __restrict__ W2n, unsigned short* __restrict__ W2nTb,
    const int* __restrict__ dst, int* __restrict__ cnt_i,
    const unsigned int* __restrict__ mask, int* __restrict__ mode)
{
    const int bid = blockIdx.x, t = threadIdx.x;
    if (bid < PREP_CVT_N){
        int i = bid * 256 + t;
        float4 a = ntld4(x + (size_t)i * 8), b = ntld4(x + (size_t)i * 8 + 4);
        ushort8 o = {f2b(a.x), f2b(a.y), f2b(a.z), f2b(a.w), f2b(b.x), f2b(b.y), f2b(b.z), f2b(b.w)};
        *(ushort8*)(xb + (size_t)i * 8) = o;
    } else if (bid < PREP_W1B_B){
        wT_region(W1e, W1tT, 0, 128, 128, (bid - PREP_W1T_B) * 256 + t);
    } else if (bid < PREP_W2T_B){
        wT_region(W1e, W1bT, 128, 64, 128, (bid - PREP_W1B_B) * 256 + t);
    } else if (bid < PREP_W2B_B){
        wT_region(W2e, W2tT, 0, 256, 64, (bid - PREP_W2T_B) * 256 + t);
    } else if (bid < PREP_W1N_B){
        wT_region(W2e, W2bT, 256, 128, 64, (bid - PREP_W2B_B) * 256 + t);
    } else if (bid < PREP_W2N_B){
        wT_region(W1n, W1nTb, 0, 256, 256, (bid - PREP_W1N_B) * 256 + t);
    } else if (bid < PREP_HIST_B){
        wT_region(W2n, W2nTb, 0, 320, 256, (bid - PREP_W2N_B) * 256 + t);
    } else if (bid < PREP_DET_B){
        int i = (bid - PREP_HIST_B) * 256 + t;
        if (i < NEDGES) atomicAdd(&cnt_i[dst[i]], 1);
    } else if (t == 0){
        bool allI32 = true, allF32 = true;
        for (int i = 0; i < 64; i++){
            unsigned int v = mask[i];
            if (!(v == 0u || v == 1u)) allI32 = false;
            if (!(v == 0u || v == 0x3F800000u)) allF32 = false;
        }
        *mode = allI32 ? 0 : (allF32 ? 1 : 2);
    }
}

// ---------------- 3-stage exclusive prefix ----------------
__global__ __launch_bounds__(256) void k_pfx1(const int* __restrict__ cnt_i, int* __restrict__ blocksum){
    __shared__ int red[256];
    const int t = threadIdx.x;
    const int i = blockIdx.x * 256 + t;
    red[t] = (i < NNODES) ? cnt_i[i] : 0;
    __syncthreads();
    for (int o = 128; o; o >>= 1){ if (t < o) red[t] += red[t + o]; __syncthreads(); }
    if (t == 0) blocksum[blockIdx.x] = red[0];
}
__global__ __launch_bounds__(128) void k_pfx2(const int* __restrict__ blocksum, int* __restrict__ blockoff){
    __shared__ int s[128];
    const int t = threadIdx.x;
    int v = (t < NB_PFX) ? blocksum[t] : 0;
    s[t] = v;
    __syncthreads();
    for (int o = 1; o < 128; o <<= 1){
        int add = (t >= o) ? s[t - o] : 0;
        __syncthreads();
        s[t] += add;
        __syncthreads();
    }
    if (t < NB_PFX) blockoff[t] = s[t] - v;
}
__global__ __launch_bounds__(256) void k_pfx3(const int* __restrict__ cnt_i, const int* __restrict__ blockoff,
                                              int* __restrict__ cursor, float* __restrict__ cntf){
    __shared__ int s[256];
    const int t = threadIdx.x;
    const int i = blockIdx.x * 256 + t;
    int v = (i < NNODES) ? cnt_i[i] : 0;
    s[t] = v;
    __syncthreads();
    for (int o = 1; o < 256; o <<= 1){
        int add = (t >= o) ? s[t - o] : 0;
        __syncthreads();
        s[t] += add;
        __syncthreads();
    }
    if (i < NNODES){
        cursor[i] = s[t] - v + blockoff[blockIdx.x];
        cntf[i] = (float)v;
    }
}

__global__ void k_scatter(const int* __restrict__ dst, int* __restrict__ cursor, int* __restrict__ eidx){
    int i = blockIdx.x * 256 + threadIdx.x;
    if (i >= NEDGES) return;
    int pos = atomicAdd(&cursor[dst[i]], 1);
    eidx[pos] = i;
}
__global__ void k_sgather(const int* __restrict__ src, const int* __restrict__ dst,
                          const int* __restrict__ eidx,
                          int* __restrict__ srcs, int* __restrict__ dsts){
    int p = blockIdx.x * 256 + threadIdx.x;
    if (p >= NEDGES) return;
    int i = eidx[p];
    srcs[p] = src[i];
    dsts[p] = dst[i];
}

// ---------------- small GEMM: out_bf16[M,N] = Ab[M,K] @ Wt[N,K] ----------------
template<int K, int N>
__global__ __launch_bounds__(256) void k_gemm_b16(
    const unsigned short* __restrict__ Ab, const unsigned short* __restrict__ Wt,
    unsigned short* __restrict__ outb, int M)
{
    __shared__ unsigned short At[64][K + 8];
    const int t = threadIdx.x;
    const int r0 = blockIdx.x * 64;
    {
        const int r = t >> 2, q = t & 3;
        const int row = r0 + r;
        const bool valid = row < M;
        const unsigned short* a = Ab + (size_t)(valid ? row : 0) * K;
        for (int kk = q * (K / 4); kk < (q + 1) * (K / 4); kk += 8){
            ushort8 u;
            if (valid) u = *(const ushort8*)(a + kk);
            else       u = (ushort8){0,0,0,0,0,0,0,0};
            *(ushort8*)&At[r][kk] = u;
        }
    }
    __syncthreads();
    const int lane = t & 63, w = t >> 6;
    const int fr = lane & 15, fq = lane >> 4;
    constexpr int NF = N / 16;
    floatx4 acc[NF] = {};
    #pragma unroll
    for (int ks = 0; ks < K / 32; ks++){
        const int k = ks * 32 + fq * 8;
        bhalf8 a = *(bhalf8*)&At[w * 16 + fr][k];
        #pragma unroll
        for (int n = 0; n < NF; n++){
            bhalf8 b = *(const bhalf8*)(Wt + (size_t)(n * 16 + fr) * K + k);
            acc[n] = __builtin_amdgcn_mfma_f32_16x16x32_bf16(a, b, acc[n], 0, 0, 0);
        }
    }
    #pragma unroll
    for (int n = 0; n < NF; n++){
        const int col = n * 16 + fr;
        #pragma unroll
        for (int rr = 0; rr < 4; rr++){
            const int row = r0 + w * 16 + fq * 4 + rr;
            if (row < M) outb[(size_t)row * N + col] = f2b(acc[n][rr]);
        }
    }
}

// ---------------- fused edge layer 1 (round-7 structure: in-kernel gather, LDS P1 + LDS Q staging) ----------------
__global__ __launch_bounds__(256) void k_edge1_fused(
    const float* __restrict__ e,
    const int* __restrict__ srcs, const int* __restrict__ dsts, const int* __restrict__ eidx,
    const unsigned short* __restrict__ W1bT, const float* __restrict__ b1e,
    const unsigned short* __restrict__ P1b, const unsigned short* __restrict__ W2bT,
    unsigned short* __restrict__ Qb, float* __restrict__ hsum)
{
    __shared__ unsigned short Cb[64][136];    // 17.4 KB
    __shared__ unsigned short P1s[64][136];   // 17.4 KB (P1 tile; reused as Q staging)
    __shared__ int dstS[64];
    const int t = threadIdx.x;
    const int p0 = blockIdx.x * 64;
    const int r = t >> 2, q = t & 3;
    // phase A: stage e rows (f32 -> bf16, nt) + P1 tile (vectorized L2)
    {
        const int p = p0 + r;
        if (q == 0) dstS[r] = dsts[p];
        const int srow = srcs[p];
        const unsigned short* pp = P1b + (size_t)srow * 128 + q * 32;
        *(ushort8*)&P1s[r][q * 32]      = *(const ushort8*)pp;
        *(ushort8*)&P1s[r][q * 32 + 8]  = *(const ushort8*)(pp + 8);
        *(ushort8*)&P1s[r][q * 32 + 16] = *(const ushort8*)(pp + 16);
        *(ushort8*)&P1s[r][q * 32 + 24] = *(const ushort8*)(pp + 24);
        const int ei = eidx[p];
        const float* ep = e + (size_t)ei * 64 + q * 16;
        float4 f0 = ntld4(ep), f1 = ntld4(ep + 4), f2 = ntld4(ep + 8), f3 = ntld4(ep + 12);
        ushort8 u0 = {f2b(f0.x), f2b(f0.y), f2b(f0.z), f2b(f0.w), f2b(f1.x), f2b(f1.y), f2b(f1.z), f2b(f1.w)};
        ushort8 u1 = {f2b(f2.x), f2b(f2.y), f2b(f2.z), f2b(f2.w), f2b(f3.x), f2b(f3.y), f2b(f3.z), f2b(f3.w)};
        *(ushort8*)&Cb[r][q * 16]     = u0;
        *(ushort8*)&Cb[r][q * 16 + 8] = u1;
    }
    __syncthreads();
    const int lane = t & 63, w = t >> 6;
    const int wm = w >> 1, wn = w & 1;
    const int fr = lane & 15, fq = lane >> 4;
    // phase B: acc1 = e_tile @ W1bT
    floatx4 acc1[2][4] = {};
    #pragma unroll
    for (int ks = 0; ks < 2; ks++){
        const int k = ks * 32 + fq * 8;
        bhalf8 a0 = *(bhalf8*)&Cb[wm * 32 + fr][k];
        bhalf8 a1 = *(bhalf8*)&Cb[wm * 32 + 16 + fr][k];
        #pragma unroll
        for (int n = 0; n < 4; n++){
            const int col = wn * 64 + n * 16 + fr;
            bhalf8 b = *(const bhalf8*)(W1bT + (size_t)col * 64 + k);
            acc1[0][n] = __builtin_amdgcn_mfma_f32_16x16x32_bf16(a0, b, acc1[0][n], 0, 0, 0);
            acc1[1][n] = __builtin_amdgcn_mfma_f32_16x16x32_bf16(a1, b, acc1[1][n], 0, 0, 0);
        }
    }
    __syncthreads();
    // phase C: e1 = leaky(acc1 + P1s + b1e) -> Cb
    #pragma unroll
    for (int m = 0; m < 2; m++){
        #pragma unroll
        for (int n = 0; n < 4; n++){
            const int col = wn * 64 + n * 16 + fr;
            const float bv = b1e[col];
            #pragma unroll
            for (int rr = 0; rr < 4; rr++){
                const int row = wm * 32 + m * 16 + fq * 4 + rr;
                const float pv = b2f(P1s[row][col]);
                Cb[row][col] = f2b(lrelu(acc1[m][n][rr] + pv + bv));
            }
        }
    }
    __syncthreads();
    // phase D: Q = e1 @ W2bT -> stage into P1s (dead)
    {
        floatx4 acc2[4] = {};
        #pragma unroll
        for (int ks = 0; ks < 4; ks++){
            const int k = ks * 32 + fq * 8;
            bhalf8 a = *(bhalf8*)&Cb[w * 16 + fr][k];
            #pragma unroll
            for (int n = 0; n < 4; n++){
                bhalf8 b = *(const bhalf8*)(W2bT + (size_t)(n * 16 + fr) * 128 + k);
                acc2[n] = __builtin_amdgcn_mfma_f32_16x16x32_bf16(a, b, acc2[n], 0, 0, 0);
            }
        }
        #pragma unroll
        for (int n = 0; n < 4; n++){
            const int col = n * 16 + fr;
            #pragma unroll
            for (int rr = 0; rr < 4; rr++){
                const int row = w * 16 + fq * 4 + rr;
                P1s[row][col] = f2b(acc2[n][rr]);
            }
        }
    }
    __syncthreads();
    // coalesced Q store (32B per thread, full lines)
    {
        unsigned short* op = Qb + (size_t)(p0 + r) * 64 + q * 16;
        ntst8u(op,     *(ushort8*)&P1s[r][q * 16]);
        ntst8u(op + 8, *(ushort8*)&P1s[r][q * 16 + 8]);
    }
    // phase E: run-reduced scatter-add of e1 to h1sum
    {
        const int col = t & 127, half = t >> 7;
        const int rbase = half * 32;
        float s = 0.f;
        int prev = dstS[rbase];
        #pragma unroll 4
        for (int rr = 0; rr < 32; rr++){
            const int rw2 = rbase + rr;
            const int d = dstS[rw2];
            if (d != prev){
                atomicAdd(&hsum[(size_t)prev * EHID + col], s);
                s = 0.f; prev = d;
            }
            s += b2f(Cb[rw2][col]);
        }
        atomicAdd(&hsum[(size_t)prev * EHID + col], s);
    }
}

// ---------------- edge layer 2 (lite) ----------------
__global__ __launch_bounds__(256) void k_edge2_lite(
    const unsigned short* __restrict__ P2b, const unsigned short* __restrict__ Qb,
    const int* __restrict__ srcs, const int* __restrict__ dsts,
    const float* __restrict__ b2e, float* __restrict__ hsum)
{
    const int t = threadIdx.x;
    const int lane = t & 63, w = t >> 6;
    const int p0 = blockIdx.x * 256 + w * 64;
    const float bias = b2e[lane];
    float s = 0.f;
    int prev = dsts[p0];
    #pragma unroll 4
    for (int i = 0; i < 64; i++){
        const int p = p0 + i;
        const int d = dsts[p];
        if (d != prev){
            atomicAdd(&hsum[(size_t)prev * EOUTD + lane], s);
            s = 0.f; prev = d;
        }
        const float q  = b2f(__builtin_nontemporal_load(&Qb[(size_t)p * 64 + lane]));
        const float pv = b2f(P2b[(size_t)srcs[p] * 64 + lane]);
        s += lrelu(pv + q + bias);
    }
    atomicAdd(&hsum[(size_t)prev * EOUTD + lane], s);
}

// ---------------- node1 + fused P2 ----------------
__global__ __launch_bounds__(256) void k_node1_p2(
    const unsigned short* __restrict__ A1b, const float* __restrict__ hsum,
    const float* __restrict__ cntf,
    const unsigned short* __restrict__ Wt, const float* __restrict__ bias,
    const unsigned short* __restrict__ W2tT,
    unsigned short* __restrict__ x1b, unsigned short* __restrict__ P2b, int M)
{
    constexpr int K = 256;
    __shared__ unsigned short At[32][K + 8];
    const int t = threadIdx.x;
    const int r0 = blockIdx.x * 32;
    {
        const int r = t >> 3, q = t & 7;
        const int row = r0 + r;
        const bool valid = row < M;
        float rinv = 0.f;
        const unsigned short* a1 = A1b;
        const float* a2 = hsum;
        if (valid){
            rinv = 1.f / fmaxf(cntf[row], 1.f);
            a1 = A1b  + (size_t)row * NIN;
            a2 = hsum + (size_t)row * EHID;
        }
        for (int kk = q * 32; kk < q * 32 + 32; kk += 8){
            ushort8 u;
            if (!valid){
                u = (ushort8){0,0,0,0,0,0,0,0};
            } else if (kk < NIN){
                u = *(const ushort8*)(a1 + kk);
            } else {
                float4 g0 = ld4(a2 + (kk - NIN)), g1 = ld4(a2 + (kk - NIN) + 4);
                u = (ushort8){f2b(g0.x*rinv), f2b(g0.y*rinv), f2b(g0.z*rinv), f2b(g0.w*rinv),
                              f2b(g1.x*rinv), f2b(g1.y*rinv), f2b(g1.z*rinv), f2b(g1.w*rinv)};
            }
            *(ushort8*)&At[r][kk] = u;
        }
    }
    __syncthreads();
    const int lane = t & 63, w = t >> 6;
    const int wm = w >> 1, wn = w & 1;
    const int fr = lane & 15, fq = lane >> 4;
    floatx4 acc[8] = {};
    #pragma unroll
    for (int ks = 0; ks < 8; ks++){
        const int k = ks * 32 + fq * 8;
        bhalf8 a = *(bhalf8*)&At[wm * 16 + fr][k];
        #pragma unroll
        for (int n = 0; n < 8; n++){
            const int col = wn * 128 + n * 16 + fr;
            bhalf8 b = *(const bhalf8*)(Wt + (size_t)col * K + k);
            acc[n] = __builtin_amdgcn_mfma_f32_16x16x32_bf16(a, b, acc[n], 0, 0, 0);
        }
    }
    __syncthreads();
    #pragma unroll
    for (int n = 0; n < 8; n++){
        const int col = wn * 128 + n * 16 + fr;
        const float bv = bias[col];
        #pragma unroll
        for (int rr = 0; rr < 4; rr++){
            const int row = r0 + wm * 16 + fq * 4 + rr;
            unsigned short ob = f2b(lrelu(acc[n][rr] + bv));
            At[wm * 16 + fq * 4 + rr][col] = ob;
            if (row < M) x1b[(size_t)row * 256 + col] = ob;
        }
    }
    __syncthreads();
    {
        floatx4 acc2[2] = {};
        #pragma unroll
        for (int ks = 0; ks < 8; ks++){
            const int k = ks * 32 + fq * 8;
            bhalf8 a = *(bhalf8*)&At[wm * 16 + fr][k];
            #pragma unroll
            for (int n = 0; n < 2; n++){
                const int col = wn * 32 + n * 16 + fr;
                bhalf8 b = *(const bhalf8*)(W2tT + (size_t)col * 256 + k);
                acc2[n] = __builtin_amdgcn_mfma_f32_16x16x32_bf16(a, b, acc2[n], 0, 0, 0);
            }
        }
        #pragma unroll
        for (int n = 0; n < 2; n++){
            const int col = wn * 32 + n * 16 + fr;
            #pragma unroll
            for (int rr = 0; rr < 4; rr++){
                const int row = r0 + wm * 16 + fq * 4 + rr;
                if (row < M) P2b[(size_t)row * 64 + col] = f2b(acc2[n][rr]);
            }
        }
    }
}

// ---------------- node2 (bf16-out only) ----------------
__global__ __launch_bounds__(256) void k_node2(
    const unsigned short* __restrict__ A1b, const float* __restrict__ hsum,
    const float* __restrict__ cntf,
    const unsigned short* __restrict__ Wt, const float* __restrict__ bias,
    unsigned short* __restrict__ outb, int M)
{
    constexpr int K = 320;
    __shared__ unsigned short At[32][K + 8];
    const int t = threadIdx.x;
    const int r0 = blockIdx.x * 32;
    {
        const int r = t >> 3, q = t & 7;
        const int row = r0 + r;
        const bool valid = row < M;
        float rinv = 0.f;
        const unsigned short* a1 = A1b;
        const float* a2 = hsum;
        if (valid){
            rinv = 1.f / fmaxf(cntf[row], 1.f);
            a1 = A1b  + (size_t)row * NHID;
            a2 = hsum + (size_t)row * EOUTD;
        }
        for (int kk = q * 40; kk < q * 40 + 40; kk += 8){
            ushort8 u;
            if (!valid){
                u = (ushort8){0,0,0,0,0,0,0,0};
            } else if (kk < NHID){
                u = *(const ushort8*)(a1 + kk);
            } else {
                float4 g0 = ld4(a2 + (kk - NHID)), g1 = ld4(a2 + (kk - NHID) + 4);
                u = (ushort8){f2b(g0.x*rinv), f2b(g0.y*rinv), f2b(g0.z*rinv), f2b(g0.w*rinv),
                              f2b(g1.x*rinv), f2b(g1.y*rinv), f2b(g1.z*rinv), f2b(g1.w*rinv)};
            }
            *(ushort8*)&At[r][kk] = u;
        }
    }
    __syncthreads();
    const int lane = t & 63, w = t >> 6;
    const int wm = w >> 1, wn = w & 1;
    const int fr = lane & 15, fq = lane >> 4;
    floatx4 acc[8] = {};
    #pragma unroll
    for (int ks = 0; ks < 10; ks++){
        const int k = ks * 32 + fq * 8;
        bhalf8 a = *(bhalf8*)&At[wm * 16 + fr][k];
        #pragma unroll
        for (int n = 0; n < 8; n++){
            const int col = wn * 128 + n * 16 + fr;
            bhalf8 b = *(const bhalf8*)(Wt + (size_t)col * K + k);
            acc[n] = __builtin_amdgcn_mfma_f32_16x16x32_bf16(a, b, acc[n], 0, 0, 0);
        }
    }
    #pragma unroll
    for (int n = 0; n < 8; n++){
        const int col = wn * 128 + n * 16 + fr;
        const float bv = bias[col];
        #pragma unroll
        for (int rr = 0; rr < 4; rr++){
            const int row = r0 + wm * 16 + fq * 4 + rr;
            if (row < M) outb[(size_t)row * 256 + col] = f2b(lrelu(acc[n][rr] + bv));
        }
    }
}

// ---------------- attention: q,k,v (x1 bf16) ----------------
__global__ __launch_bounds__(256) void k_attn_qkv(
    const unsigned short* __restrict__ x1b, const int* __restrict__ col_idx,
    const float* __restrict__ pe,
    const float* __restrict__ Wq, const float* __restrict__ Wk, const float* __restrict__ Wv,
    float* __restrict__ qo, float* __restrict__ ko, float* __restrict__ vo)
{
    __shared__ float c[256];
    const int i = blockIdx.x, t = threadIdx.x;
    const int col = col_idx[i];
    c[t] = b2f(x1b[(size_t)col * 256 + t]) + pe[i * 256 + t];
    __syncthreads();
    float aq = 0.f, ak = 0.f, av = 0.f;
    #pragma unroll 4
    for (int kk = 0; kk < 256; kk++){
        float cv = c[kk];
        aq += cv * Wq[kk * 256 + t];
        ak += cv * Wk[kk * 256 + t];
        av += cv * Wv[kk * 256 + t];
    }
    qo[i * 256 + t] = aq; ko[i * 256 + t] = ak; vo[i * 256 + t] = av;
}

// ---------------- attention: dist ----------------
__global__ __launch_bounds__(128) void k_attn_dist(
    const float* __restrict__ q, const float* __restrict__ k, float* __restrict__ dist)
{
    __shared__ float qr[256];
    __shared__ float red[128];
    const int i = blockIdx.x, t = threadIdx.x;
    qr[t] = q[i * 256 + t]; qr[t + 128] = q[i * 256 + t + 128];
    __syncthreads();
    float s = 0.f;
    #pragma unroll 4
    for (int kk = 0; kk < 256; kk++) s += qr[kk] * k[t * 256 + kk];
    s *= 0.0625f;
    red[t] = s; __syncthreads();
    for (int off = 64; off; off >>= 1){ if (t < off) red[t] = fmaxf(red[t], red[t + off]); __syncthreads(); }
    float m = red[0]; __syncthreads();
    float ex = expf(s - m);
    red[t] = ex; __syncthreads();
    for (int off = 64; off; off >>= 1){ if (t < off) red[t] += red[t + off]; __syncthreads(); }
    dist[i * 128 + t] = ex / red[0];
}

// ---------------- attention tail ----------------
__global__ __launch_bounds__(256) void k_attn_out(
    const float* __restrict__ dist, const float* __restrict__ v,
    const float* __restrict__ Wref, const float* __restrict__ bref,
    const float* __restrict__ Wc, const float* __restrict__ bep,
    float* __restrict__ colWc)
{
    __shared__ float dr[128];
    __shared__ float c2[256];
    __shared__ float nc[256];
    const int i = blockIdx.x, t = threadIdx.x;
    if (t < 128) dr[t] = dist[i * 128 + t];
    __syncthreads();
    float s = 0.f;
    #pragma unroll 4
    for (int j = 0; j < 128; j++) s += dr[j] * v[j * 256 + t];
    c2[t] = 2.f * s;
    __syncthreads();
    float a = 0.f;
    #pragma unroll 4
    for (int kk = 0; kk < 256; kk++) a += c2[kk] * Wref[kk * 256 + t];
    a += bref[t];
    nc[t] = 1.f / (1.f + expf(-a));
    __syncthreads();
    if (t < 64){
        float o = 0.f;
        #pragma unroll 4
        for (int kk = 0; kk < 256; kk++) o += nc[kk] * Wc[kk * 64 + t];
        colWc[i * 64 + t] = o + bep[t];
    }
}

// ---------------- rowWr = x2b[row_idx] @ Wr ----------------
__global__ __launch_bounds__(256) void k_rowwr(
    const unsigned short* __restrict__ x2b, const int* __restrict__ row_idx,
    const float* __restrict__ Wr, float* __restrict__ rw)
{
    __shared__ unsigned short A[16][264];
    const int t = threadIdx.x;
    const int r0 = blockIdx.x * 16;
    const int rl = t >> 4, cg = t & 15;
    const int ridx = row_idx[r0 + rl];
    const unsigned short* ar = x2b + (size_t)ridx * 256;
    for (int i = cg; i < 32; i += 16) *(ushort8*)&A[rl][i * 8] = *(const ushort8*)(ar + i * 8);
    __syncthreads();
    float acc[4] = {0.f, 0.f, 0.f, 0.f};
    #pragma unroll 4
    for (int kk = 0; kk < 256; kk++){
        float4 w = ld4(Wr + (size_t)kk * 64 + cg * 4);
        float a = b2f(A[rl][kk]);
        acc[0] += a * w.x; acc[1] += a * w.y; acc[2] += a * w.z; acc[3] += a * w.w;
    }
    *(float4*)(rw + (size_t)(r0 + rl) * 64 + cg * 4) = make_float4(acc[0], acc[1], acc[2], acc[3]);
}

// ---------------- fused: pred -> d_out (nt), imputation, classifier, log_softmax ----------------
__global__ __launch_bounds__(256) void k_pred8(
    const float* __restrict__ rowWr, const float* __restrict__ colWc,
    const void* __restrict__ maskp, const int* __restrict__ modep,
    const float* __restrict__ real, const float* __restrict__ Wcls, const float* __restrict__ bcls,
    float* __restrict__ out)
{
    __shared__ float colWc_s[8192];
    __shared__ float rowWr_s[8 * 64];
    __shared__ unsigned char mask_s[8 * 128];
    __shared__ float part[4][80];
    __shared__ float logits_s[80];
    const int t  = threadIdx.x;
    const int r0 = blockIdx.x * 8;
    const int mode = *modep;
    for (int idx = t; idx < 2048; idx += 256)
        *(float4*)&colWc_s[idx * 4] = ld4(colWc + idx * 4);
    for (int idx = t; idx < 128; idx += 256)
        *(float4*)&rowWr_s[idx * 4] = ld4(rowWr + (size_t)r0 * 64 + idx * 4);
    for (int idx = t; idx < 1024; idx += 256){
        const int g = idx >> 7, c = idx & 127;
        const int gi = (r0 + g) * 128 + c;
        bool m;
        if (mode == 2)      m = ((const unsigned char*)maskp)[gi] != 0;
        else if (mode == 0) m = ((const int*)maskp)[gi] != 0;
        else                m = ((const float*)maskp)[gi] != 0.f;
        mask_s[idx] = m ? 1 : 0;
    }
    __syncthreads();

    float acc[8][10];
    #pragma unroll
    for (int g = 0; g < 8; g++)
        #pragma unroll
        for (int c = 0; c < 10; c++) acc[g][c] = 0.f;
    float* pred = out + RROWS * NCLS;

    #pragma unroll 1
    for (int i = 0; i < 8; i++){
        const int e4   = i * 256 + t;
        const int base = e4 * 4;
        const int c = base >> 6;
        const int j = base & 63;
        float4 cw = ld4(&colWc_s[c * 64 + j]);
        float w40[40];
        #pragma unroll
        for (int u = 0; u < 10; u++){
            float4 wv = ld4(Wcls + (size_t)base * 10 + u * 4);
            w40[u*4+0] = wv.x; w40[u*4+1] = wv.y; w40[u*4+2] = wv.z; w40[u*4+3] = wv.w;
        }
        #pragma unroll
        for (int g = 0; g < 8; g++){
            const int rr = r0 + g;
            float4 rwv = ld4(&rowWr_s[g * 64 + j]);
            float4 p;
            p.x = lrelu(rwv.x + cw.x); p.y = lrelu(rwv.y + cw.y);
            p.z = lrelu(rwv.z + cw.z); p.w = lrelu(rwv.w + cw.w);
            ntst4(pred + (size_t)rr * 8192 + base, p);
            float4 im = p;
            if (mask_s[g * 128 + c]) im = ntld4(real + (size_t)rr * 8192 + base);
            #pragma unroll
            for (int cls = 0; cls < 10; cls++){
                acc[g][cls] += im.x * w40[cls]      + im.y * w40[10 + cls]
                             + im.z * w40[20 + cls] + im.w * w40[30 + cls];
            }
        }
    }
    #pragma unroll
    for (int g = 0; g < 8; g++)
        #pragma unroll
        for (int cls = 0; cls < 10; cls++){
            float v = acc[g][cls];
            for (int off = 32; off; off >>= 1) v += __shfl_down(v, off, 64);
            acc[g][cls] = v;
        }
    const int wid = t >> 6, lane = t & 63;
    if (lane == 0){
        #pragma unroll
        for (int g = 0; g < 8; g++)
            #pragma unroll
            for (int cls = 0; cls < 10; cls++) part[wid][g * 10 + cls] = acc[g][cls];
    }
    __syncthreads();
    if (t < 80) logits_s[t] = part[0][t] + part[1][t] + part[2][t] + part[3][t] + bcls[t % 10];
    __syncthreads();
    if (t < 8){
        float m = -1e30f;
        #pragma unroll
        for (int cls = 0; cls < 10; cls++) m = fmaxf(m, logits_s[t * 10 + cls]);
        float se = 0.f;
        #pragma unroll
        for (int cls = 0; cls < 10; cls++) se += expf(logits_s[t * 10 + cls] - m);
        float ls = logf(se) + m;
        #pragma unroll
        for (int cls = 0; cls < 10; cls++) out[(r0 + t) * 10 + cls] = logits_s[t * 10 + cls] - ls;
    }
}

extern "C" void kernel_launch(void* const* d_in, const int* in_sizes, int n_in,
                              void* d_out, int out_size, void* d_ws, size_t ws_size,
                              hipStream_t stream)
{
    const float* x      = (const float*)d_in[0];
    const float* e      = (const float*)d_in[1];
    const int*   src    = (const int*)d_in[2];
    const int*   dst    = (const int*)d_in[3];
    const int*   row_idx= (const int*)d_in[4];
    const int*   col_idx= (const int*)d_in[5];
    const float* real   = (const float*)d_in[6];
    const void*  mask   = d_in[7];
    const float* W1e    = (const float*)d_in[8];
    const float* b1e    = (const float*)d_in[9];
    const float* W1n    = (const float*)d_in[10];
    const float* b1n    = (const float*)d_in[11];
    const float* W2e    = (const float*)d_in[12];
    const float* b2e    = (const float*)d_in[13];
    const float* W2n    = (const float*)d_in[14];
    const float* b2n    = (const float*)d_in[15];
    const float* pe     = (const float*)d_in[16];
    const float* Wq     = (const float*)d_in[17];
    const float* Wk     = (const float*)d_in[18];
    const float* Wv     = (const float*)d_in[19];
    const float* Wref   = (const float*)d_in[20];
    const float* bref   = (const float*)d_in[21];
    const float* Wr     = (const float*)d_in[22];
    const float* Wc     = (const float*)d_in[23];
    const float* bep    = (const float*)d_in[24];
    const float* Wcls   = (const float*)d_in[25];
    const float* bcls   = (const float*)d_in[26];

    float* ws = (float*)d_ws;
    size_t off = 0;
    float* h1sum = ws + off; off += (size_t)NNODES * EHID;
    float* h2sum = ws + off; off += (size_t)NNODES * EOUTD;
    int*   cnt_i = (int*)(ws + off); off += NNODES;
    const size_t zero_floats = off;
    float* cntf  = ws + off; off += NNODES;
    int*   cursor= (int*)(ws + off); off += NNODES;
    int*   srcs  = (int*)(ws + off); off += NEDGES;
    int*   dsts  = (int*)(ws + off); off += NEDGES;
    int*   eidx  = (int*)(ws + off); off += NEDGES;
    unsigned short* xb    = (unsigned short*)(ws + off); off += (size_t)NNODES * NIN  / 2;
    unsigned short* x1b   = (unsigned short*)(ws + off); off += (size_t)NNODES * NHID / 2;
    unsigned short* x2b   = (unsigned short*)(ws + off); off += (size_t)NNODES * NOUTD / 2;
    unsigned short* W1tT  = (unsigned short*)(ws + off); off += 128 * 128 / 2;
    unsigned short* W1bT  = (unsigned short*)(ws + off); off += 128 * 64 / 2;
    unsigned short* W2tT  = (unsigned short*)(ws + off); off += 64 * 256 / 2;
    unsigned short* W2bT  = (unsigned short*)(ws + off); off += 64 * 128 / 2;
    unsigned short* W1nTb = (unsigned short*)(ws + off); off += 256 * 256 / 2;
    unsigned short* W2nTb = (unsigned short*)(ws + off); off += 256 * 320 / 2;
    unsigned short* P1b   = (unsigned short*)(ws + off); off += (size_t)NNODES * 128 / 2;
    unsigned short* P2b   = (unsigned short*)(ws + off); off += (size_t)NNODES * 64 / 2;
    float* qb    = ws + off; off += 128 * 256;
    float* kb    = ws + off; off += 128 * 256;
    float* vb    = ws + off; off += 128 * 256;
    float* distb = ws + off; off += 128 * 128;
    float* colWc = ws + off; off += 128 * 64;
    float* rowWrb= ws + off; off += (size_t)RROWS * EOUTD;
    int*   modep = (int*)(ws + off); off += 4;
    int*   blocksum = (int*)(ws + off); off += 128;
    int*   blockoff = (int*)(ws + off); off += 128;
    // Q bf16 (sorted, 61MB). ws if it fits, else borrow pred region of d_out
    // (Q fully consumed by k_edge2_lite before k_pred8 writes pred).
    unsigned short* Qb;
    size_t need = (off + (size_t)NEDGES * 32) * sizeof(float);
    if (ws_size >= need) Qb = (unsigned short*)(ws + off);
    else                 Qb = (unsigned short*)((float*)d_out + (size_t)RROWS * NCLS);

    (void)hipMemsetAsync(d_ws, 0, zero_floats * sizeof(float), stream);
    k_prep<<<PREP_TOTAL, 256, 0, stream>>>(x, xb, W1e, W1tT, W1bT, W2e, W2tT, W2bT,
                                           W1n, W1nTb, W2n, W2nTb, dst, cnt_i,
                                           (const unsigned int*)mask, modep);
    k_pfx1<<<NB_PFX, 256, 0, stream>>>(cnt_i, blocksum);
    k_pfx2<<<1, 128, 0, stream>>>(blocksum, blockoff);
    k_pfx3<<<NB_PFX, 256, 0, stream>>>(cnt_i, blockoff, cursor, cntf);
    k_scatter<<<(NEDGES + 255) / 256, 256, 0, stream>>>(dst, cursor, eidx);
    k_sgather<<<(NEDGES + 255) / 256, 256, 0, stream>>>(src, dst, eidx, srcs, dsts);
    k_gemm_b16<128, 128><<<(NNODES + 63) / 64, 256, 0, stream>>>(xb, W1tT, P1b, NNODES);
    k_edge1_fused<<<NEDGES / 64, 256, 0, stream>>>(e, srcs, dsts, eidx, W1bT, b1e, P1b, W2bT, Qb, h1sum);
    k_node1_p2<<<(NNODES + 31) / 32, 256, 0, stream>>>(xb, h1sum, cntf, W1nTb, b1n, W2tT, x1b, P2b, NNODES);
    k_edge2_lite<<<NEDGES / 256, 256, 0, stream>>>(P2b, Qb, srcs, dsts, b2e, h2sum);
    k_node2<<<(NNODES + 31) / 32, 256, 0, stream>>>(x1b, h2sum, cntf, W2nTb, b2n, x2b, NNODES);
    k_attn_qkv<<<128, 256, 0, stream>>>(x1b, col_idx, pe, Wq, Wk, Wv, qb, kb, vb);
    k_attn_dist<<<128, 128, 0, stream>>>(qb, kb, distb);
    k_attn_out<<<128, 256, 0, stream>>>(distb, vb, Wref, bref, Wc, bep, colWc);
    k_rowwr<<<RROWS / 16, 256, 0, stream>>>(x2b, row_idx, Wr, rowWrb);
    k_pred8<<<RROWS / 8, 256, 0, stream>>>(rowWrb, colWc, mask, modep, real, Wcls, bcls, (float*)d_out);
}